// Round 5
// baseline (859.849 us; speedup 1.0000x reference)
//
#include <hip/hip_runtime.h>

#define NN 50000
#define NE 800000
#define EP (NE + NN)      // edges + self loops = 850000
#define NG 128
#define F 128
#define SW 140            // Ws row stride (floats), fits swizzle range [0,140)
// injective W column swizzle: c + 4*(c/32). 16 col-groups -> all banks at 2-way (free).
#define SWZ(c) ((c) + (((c) >> 5) << 2))

__device__ inline void fma4(float4& a, float s, const float4& b) {
    a.x = fmaf(s, b.x, a.x); a.y = fmaf(s, b.y, a.y);
    a.z = fmaf(s, b.z, a.z); a.w = fmaf(s, b.w, a.w);
}

// C[N,128] = A[N,128] @ W[128,128], fp32. Block tile 128x128, thread tile 8x8.
// A stored with per-8-row column rotation (rot = 8*((row>>3)&3)) so the 4 rg
// addresses per wave land on bank offsets {0,8,16,24} -> conflict-free.
__global__ __launch_bounds__(256, 1) void gemm_tiled(const float* __restrict__ A,
                                                     const float* __restrict__ W,
                                                     float* __restrict__ C, int N) {
    __shared__ float As[128 * 128];   // [row][(k+rot)&127]
    __shared__ float Ws[128 * SW];    // [k][SWZ(col)]
    const int tid = threadIdx.x;
    const int row0 = blockIdx.x * 128;
#pragma unroll
    for (int i = 0; i < 16; ++i) {
        const int idx = i * 256 + tid;          // 0..4095
        const int r = idx >> 5;                 // k-row for W, node-row for A
        const int c4 = (idx & 31) << 2;
        const float4 wv = *(const float4*)(W + r * F + c4);
        *(float4*)(Ws + r * SW + SWZ(c4)) = wv;
        const int gr = row0 + r;
        const float4 av = (gr < N) ? *(const float4*)(A + (size_t)gr * F + c4)
                                   : make_float4(0.f, 0.f, 0.f, 0.f);
        *(float4*)(As + r * 128 + ((c4 + 8 * ((r >> 3) & 3)) & 127)) = av;
    }
    __syncthreads();
    const int rg = tid >> 4, cg = tid & 15;
    const int r0 = rg * 8, c0 = cg * 8;
    const int rot_a = 8 * (rg & 3);             // uniform over this thread's 8 rows
    const int co0 = SWZ(c0);
    const int co1 = SWZ(c0 + 4);
    float4 acc[8][2] = {};
    for (int k4 = 0; k4 < F; k4 += 4) {
        const int ka = (k4 + rot_a) & 127;
        float4 a[8];
#pragma unroll
        for (int r = 0; r < 8; ++r) a[r] = *(const float4*)(As + (r0 + r) * 128 + ka);
#pragma unroll
        for (int j = 0; j < 4; ++j) {
            const float4 w0 = *(const float4*)(Ws + (k4 + j) * SW + co0);
            const float4 w1 = *(const float4*)(Ws + (k4 + j) * SW + co1);
#pragma unroll
            for (int r = 0; r < 8; ++r) {
                const float aj = ((const float*)&a[r])[j];
                fma4(acc[r][0], aj, w0);
                fma4(acc[r][1], aj, w1);
            }
        }
    }
#pragma unroll
    for (int r = 0; r < 8; ++r) {
        const int gr = row0 + r0 + r;
        if (gr < N) {
            *(float4*)(C + (size_t)gr * F + c0) = acc[r][0];
            *(float4*)(C + (size_t)gr * F + c0 + 4) = acc[r][1];
        }
    }
}

// per-node attention scores: asrc[n] = h[n,:]@att_src, adst[n] = h[n,:]@att_dst
__global__ void node_scores(const float* __restrict__ h, const float* __restrict__ as,
                            const float* __restrict__ ad, float* __restrict__ asrc,
                            float* __restrict__ adst, int N) {
    const int node = blockIdx.x * 4 + (threadIdx.x >> 6);
    const int lane = threadIdx.x & 63;
    if (node >= N) return;
    const float* hr = h + (size_t)node * F;
    float v1 = hr[lane] * as[lane] + hr[lane + 64] * as[lane + 64];
    float v2 = hr[lane] * ad[lane] + hr[lane + 64] * ad[lane + 64];
    for (int o = 32; o; o >>= 1) { v1 += __shfl_xor(v1, o); v2 += __shfl_xor(v2, o); }
    if (lane == 0) { asrc[node] = v1; adst[node] = v2; }
}

// ---- CSR build: histogram -> scan -> scatter ----
__global__ void hist_deg(const int* __restrict__ ei, int* __restrict__ deg) {
    const int e = blockIdx.x * blockDim.x + threadIdx.x;
    if (e >= EP) return;
    const int d = (e < NE) ? ei[NE + e] : e - NE;
    atomicAdd(deg + d, 1);
}

__global__ void scan_rows(const int* __restrict__ deg, int* __restrict__ row_start) {
    __shared__ int part[1024];
    const int t = threadIdx.x;
    const int CH = (NN + 1023) / 1024;
    const int lo = t * CH, hi = min(lo + CH, NN);
    int s = 0;
    for (int i = lo; i < hi; ++i) s += deg[i];
    part[t] = s;
    __syncthreads();
    for (int o = 1; o < 1024; o <<= 1) {
        int v = (t >= o) ? part[t - o] : 0;
        __syncthreads();
        part[t] += v;
        __syncthreads();
    }
    int run = part[t] - s;
    for (int i = lo; i < hi; ++i) { row_start[i] = run; run += deg[i]; }
    if (t == 1023) row_start[NN] = part[1023];
}

__global__ void scatter_csr(const int* __restrict__ ei, const int* __restrict__ row_start,
                            int* __restrict__ cnt, int* __restrict__ csr_src) {
    const int e = blockIdx.x * blockDim.x + threadIdx.x;
    if (e >= EP) return;
    int s, d;
    if (e < NE) { s = ei[e]; d = ei[NE + e]; } else { s = d = e - NE; }
    const int pos = row_start[d] + atomicAdd(cnt + d, 1);
    csr_src[pos] = s;
}

// ---- GAT gather: one wave per dst; single pass (scale by 1/den at the end) ----
__global__ void gat_gather(const int* __restrict__ row_start, const int* __restrict__ csr_src,
                           const float* __restrict__ asrc, const float* __restrict__ adst,
                           const float* __restrict__ h, const float* __restrict__ bias,
                           float* __restrict__ out) {
    const int n = blockIdx.x * 4 + (threadIdx.x >> 6);
    const int lane = threadIdx.x & 63;
    if (n >= NN) return;
    const int lo = row_start[n], hi = row_start[n + 1];
    const float adn = adst[n];
    float den = 0.f;
    float2 acc0 = {0.f, 0.f}, acc1 = {0.f, 0.f};
    int i = lo;
    for (; i + 2 <= hi; i += 2) {
        const int s0 = csr_src[i], s1 = csr_src[i + 1];
        float sc0 = asrc[s0] + adn; sc0 = sc0 > 0.f ? sc0 : 0.2f * sc0;
        float sc1 = asrc[s1] + adn; sc1 = sc1 > 0.f ? sc1 : 0.2f * sc1;
        const float e0 = __expf(sc0), e1 = __expf(sc1);
        const float2 h0 = *(const float2*)(h + (size_t)s0 * F + lane * 2);
        const float2 h1 = *(const float2*)(h + (size_t)s1 * F + lane * 2);
        den += e0 + e1;
        acc0.x = fmaf(e0, h0.x, acc0.x); acc0.y = fmaf(e0, h0.y, acc0.y);
        acc1.x = fmaf(e1, h1.x, acc1.x); acc1.y = fmaf(e1, h1.y, acc1.y);
    }
    if (i < hi) {
        const int s0 = csr_src[i];
        float sc0 = asrc[s0] + adn; sc0 = sc0 > 0.f ? sc0 : 0.2f * sc0;
        const float e0 = __expf(sc0);
        const float2 h0 = *(const float2*)(h + (size_t)s0 * F + lane * 2);
        den += e0;
        acc0.x = fmaf(e0, h0.x, acc0.x); acc0.y = fmaf(e0, h0.y, acc0.y);
    }
    const float inv = 1.f / den;     // den > 0 (self loop)
    float v0 = (acc0.x + acc1.x) * inv + bias[lane * 2];
    float v1 = (acc0.y + acc1.y) * inv + bias[lane * 2 + 1];
    float2* o = (float2*)(out + (size_t)n * F + lane * 2);
    *o = make_float2(v0 > 0.f ? v0 : 0.f, v1 > 0.f ? v1 : 0.f);
}

__global__ void make_dinv(const int* __restrict__ row_start, float* __restrict__ dinv) {
    const int n = blockIdx.x * blockDim.x + threadIdx.x;
    if (n >= NN) return;
    dinv[n] = rsqrtf((float)(row_start[n + 1] - row_start[n]));
}

__global__ void graph_cnt(const int* __restrict__ batch, int* __restrict__ cnt) {
    const int n = blockIdx.x * blockDim.x + threadIdx.x;
    if (n >= NN) return;
    atomicAdd(cnt + batch[n], 1);
}

__global__ void init_out(const int* __restrict__ cnt, const float* __restrict__ bf,
                         float* __restrict__ out, float* __restrict__ ginv) {
    const int g = threadIdx.x;   // 128
    ginv[g] = 1.f / fmaxf((float)cnt[g], 1.f);
    out[g * 2]     = bf[0];
    out[g * 2 + 1] = bf[1];
}

// ---- GCN gather with fused mean-pool + head: out[g,c] += (relu(v)@Wf[:,c])/cnt_g
__global__ void gcn_gather_pool(const int* __restrict__ row_start, const int* __restrict__ csr_src,
                                const float* __restrict__ dinv, const float* __restrict__ h,
                                const float* __restrict__ bias, const int* __restrict__ batch,
                                const float* __restrict__ ginv, const float* __restrict__ Wf,
                                float* __restrict__ out) {
    const int n = blockIdx.x * 4 + (threadIdx.x >> 6);
    const int lane = threadIdx.x & 63;
    if (n >= NN) return;
    const int lo = row_start[n], hi = row_start[n + 1];
    const float dn = dinv[n];
    float2 acc0 = {0.f, 0.f}, acc1 = {0.f, 0.f};
    int i = lo;
    for (; i + 2 <= hi; i += 2) {
        const int s0 = csr_src[i], s1 = csr_src[i + 1];
        const float w0 = dinv[s0], w1 = dinv[s1];
        const float2 h0 = *(const float2*)(h + (size_t)s0 * F + lane * 2);
        const float2 h1 = *(const float2*)(h + (size_t)s1 * F + lane * 2);
        acc0.x = fmaf(w0, h0.x, acc0.x); acc0.y = fmaf(w0, h0.y, acc0.y);
        acc1.x = fmaf(w1, h1.x, acc1.x); acc1.y = fmaf(w1, h1.y, acc1.y);
    }
    if (i < hi) {
        const int s0 = csr_src[i];
        const float w0 = dinv[s0];
        const float2 h0 = *(const float2*)(h + (size_t)s0 * F + lane * 2);
        acc0.x = fmaf(w0, h0.x, acc0.x); acc0.y = fmaf(w0, h0.y, acc0.y);
    }
    float v0 = (acc0.x + acc1.x) * dn + bias[lane * 2];
    float v1 = (acc0.y + acc1.y) * dn + bias[lane * 2 + 1];
    v0 = v0 > 0.f ? v0 : 0.f;
    v1 = v1 > 0.f ? v1 : 0.f;
    // project to 2 classes and reduce across the wave (128 feats = 64 lanes x 2)
    float p0 = v0 * Wf[(lane * 2) * 2]     + v1 * Wf[(lane * 2 + 1) * 2];
    float p1 = v0 * Wf[(lane * 2) * 2 + 1] + v1 * Wf[(lane * 2 + 1) * 2 + 1];
    for (int o = 32; o; o >>= 1) { p0 += __shfl_xor(p0, o); p1 += __shfl_xor(p1, o); }
    if (lane == 0) {
        const int g = batch[n];
        const float gi = ginv[g];
        atomicAdd(out + g * 2,     p0 * gi);
        atomicAdd(out + g * 2 + 1, p1 * gi);
    }
}

extern "C" void kernel_launch(void* const* d_in, const int* in_sizes, int n_in,
                              void* d_out, int out_size, void* d_ws, size_t ws_size,
                              hipStream_t stream) {
    const float* x       = (const float*)d_in[0];
    const float* W1      = (const float*)d_in[1];
    const float* att_src = (const float*)d_in[2];
    const float* att_dst = (const float*)d_in[3];
    const float* b1      = (const float*)d_in[4];
    const float* W2      = (const float*)d_in[5];
    const float* b2      = (const float*)d_in[6];
    const float* Wf      = (const float*)d_in[7];
    const float* bf      = (const float*)d_in[8];
    const int*   ei      = (const int*)d_in[9];
    const int*   batch   = (const int*)d_in[10];
    float* out = (float*)d_out;

    float* ws        = (float*)d_ws;
    float* h1        = ws;                       // [NN*F]
    float* hg        = h1 + (size_t)NN * F;      // [NN*F]
    float* h2        = hg + (size_t)NN * F;      // [NN*F]
    float* asrc      = h2 + (size_t)NN * F;      // [NN]
    float* adst      = asrc + NN;                // [NN]
    float* dinv      = adst + NN;                // [NN]
    float* ginv      = dinv + NN;                // [NG]
    int*   gcnt      = (int*)(ginv + NG);        // [NG]
    int*   deg       = gcnt + NG;                // [NN] histogram, then scatter cursor
    int*   row_start = deg + NN;                 // [NN+1]
    int*   csr_src   = row_start + NN + 1;       // [EP]

    // CSR build (independent of feature path)
    hipMemsetAsync(deg, 0, NN * sizeof(int), stream);
    hipMemsetAsync(gcnt, 0, NG * sizeof(int), stream);
    hist_deg<<<(EP + 255) / 256, 256, 0, stream>>>(ei, deg);
    scan_rows<<<1, 1024, 0, stream>>>(deg, row_start);
    hipMemsetAsync(deg, 0, NN * sizeof(int), stream);
    scatter_csr<<<(EP + 255) / 256, 256, 0, stream>>>(ei, row_start, deg, csr_src);
    graph_cnt<<<(NN + 255) / 256, 256, 0, stream>>>(batch, gcnt);
    init_out<<<1, NG, 0, stream>>>(gcnt, bf, out, ginv);

    gemm_tiled<<<(NN + 127) / 128, 256, 0, stream>>>(x, W1, h1, NN);
    node_scores<<<(NN + 3) / 4, 256, 0, stream>>>(h1, att_src, att_dst, asrc, adst, NN);
    gat_gather<<<(NN + 3) / 4, 256, 0, stream>>>(row_start, csr_src, asrc, adst, h1, b1, hg);
    gemm_tiled<<<(NN + 127) / 128, 256, 0, stream>>>(hg, W2, h2, NN);
    make_dinv<<<(NN + 255) / 256, 256, 0, stream>>>(row_start, dinv);
    gcn_gather_pool<<<(NN + 3) / 4, 256, 0, stream>>>(row_start, csr_src, dinv, h2, b2,
                                                      batch, ginv, Wf, out);
}

// Round 6
// 468.681 us; speedup vs baseline: 1.8346x; 1.8346x over previous
//
#include <hip/hip_runtime.h>

#define NN 50000
#define NE 800000
#define EP (NE + NN)      // edges + self loops = 850000
#define NG 128
#define F 128
#define SW 140            // Ws row stride (floats), fits swizzle range [0,140)
// injective W column swizzle: c + 4*(c/32). 16 col-groups -> all banks at 2-way (free).
#define SWZ(c) ((c) + (((c) >> 5) << 2))

__device__ inline void fma4(float4& a, float s, const float4& b) {
    a.x = fmaf(s, b.x, a.x); a.y = fmaf(s, b.y, a.y);
    a.z = fmaf(s, b.z, a.z); a.w = fmaf(s, b.w, a.w);
}

// C[N,128] = A[N,128] @ W[128,128], fp32. Block tile 128x128, thread tile 8x8.
__global__ __launch_bounds__(256, 1) void gemm_tiled(const float* __restrict__ A,
                                                     const float* __restrict__ W,
                                                     float* __restrict__ C, int N) {
    __shared__ float As[128 * 128];   // [row][(k+rot)&127]
    __shared__ float Ws[128 * SW];    // [k][SWZ(col)]
    const int tid = threadIdx.x;
    const int row0 = blockIdx.x * 128;
#pragma unroll
    for (int i = 0; i < 16; ++i) {
        const int idx = i * 256 + tid;          // 0..4095
        const int r = idx >> 5;                 // k-row for W, node-row for A
        const int c4 = (idx & 31) << 2;
        const float4 wv = *(const float4*)(W + r * F + c4);
        *(float4*)(Ws + r * SW + SWZ(c4)) = wv;
        const int gr = row0 + r;
        const float4 av = (gr < N) ? *(const float4*)(A + (size_t)gr * F + c4)
                                   : make_float4(0.f, 0.f, 0.f, 0.f);
        *(float4*)(As + r * 128 + ((c4 + 8 * ((r >> 3) & 3)) & 127)) = av;
    }
    __syncthreads();
    const int rg = tid >> 4, cg = tid & 15;
    const int r0 = rg * 8, c0 = cg * 8;
    const int rot_a = 8 * (rg & 3);
    const int co0 = SWZ(c0);
    const int co1 = SWZ(c0 + 4);
    float4 acc[8][2] = {};
    for (int k4 = 0; k4 < F; k4 += 4) {
        const int ka = (k4 + rot_a) & 127;
        float4 a[8];
#pragma unroll
        for (int r = 0; r < 8; ++r) a[r] = *(const float4*)(As + (r0 + r) * 128 + ka);
#pragma unroll
        for (int j = 0; j < 4; ++j) {
            const float4 w0 = *(const float4*)(Ws + (k4 + j) * SW + co0);
            const float4 w1 = *(const float4*)(Ws + (k4 + j) * SW + co1);
#pragma unroll
            for (int r = 0; r < 8; ++r) {
                const float aj = ((const float*)&a[r])[j];
                fma4(acc[r][0], aj, w0);
                fma4(acc[r][1], aj, w1);
            }
        }
    }
#pragma unroll
    for (int r = 0; r < 8; ++r) {
        const int gr = row0 + r0 + r;
        if (gr < N) {
            *(float4*)(C + (size_t)gr * F + c0) = acc[r][0];
            *(float4*)(C + (size_t)gr * F + c0 + 4) = acc[r][1];
        }
    }
}

// per-node attention scores: asrc[n] = h[n,:]@att_src, adst[n] = h[n,:]@att_dst
__global__ void node_scores(const float* __restrict__ h, const float* __restrict__ as,
                            const float* __restrict__ ad, float* __restrict__ asrc,
                            float* __restrict__ adst, int N) {
    const int node = blockIdx.x * 4 + (threadIdx.x >> 6);
    const int lane = threadIdx.x & 63;
    if (node >= N) return;
    const float* hr = h + (size_t)node * F;
    float v1 = hr[lane] * as[lane] + hr[lane + 64] * as[lane + 64];
    float v2 = hr[lane] * ad[lane] + hr[lane + 64] * ad[lane + 64];
    for (int o = 32; o; o >>= 1) { v1 += __shfl_xor(v1, o); v2 += __shfl_xor(v2, o); }
    if (lane == 0) { asrc[node] = v1; adst[node] = v2; }
}

// ---- CSR build: histogram -> scan -> scatter ----
__global__ void hist_deg(const int* __restrict__ ei, int* __restrict__ deg) {
    const int e = blockIdx.x * blockDim.x + threadIdx.x;
    if (e >= EP) return;
    const int d = (e < NE) ? ei[NE + e] : e - NE;
    atomicAdd(deg + d, 1);
}

__global__ void scan_rows(const int* __restrict__ deg, int* __restrict__ row_start) {
    __shared__ int part[1024];
    const int t = threadIdx.x;
    const int CH = (NN + 1023) / 1024;
    const int lo = t * CH, hi = min(lo + CH, NN);
    int s = 0;
    for (int i = lo; i < hi; ++i) s += deg[i];
    part[t] = s;
    __syncthreads();
    for (int o = 1; o < 1024; o <<= 1) {
        int v = (t >= o) ? part[t - o] : 0;
        __syncthreads();
        part[t] += v;
        __syncthreads();
    }
    int run = part[t] - s;
    for (int i = lo; i < hi; ++i) { row_start[i] = run; run += deg[i]; }
    if (t == 1023) row_start[NN] = part[1023];
}

__global__ void scatter_csr(const int* __restrict__ ei, const int* __restrict__ row_start,
                            int* __restrict__ cnt, int* __restrict__ csr_src) {
    const int e = blockIdx.x * blockDim.x + threadIdx.x;
    if (e >= EP) return;
    int s, d;
    if (e < NE) { s = ei[e]; d = ei[NE + e]; } else { s = d = e - NE; }
    const int pos = row_start[d] + atomicAdd(cnt + d, 1);
    csr_src[pos] = s;
}

// ---- GAT gather: one wave per dst node. Indices + exp-weights are prefetched
// 64-wide (one coalesced load + one gather per chunk), then the per-edge loop
// is shuffle-broadcast + one h-row load: the dependent chain is 1 memory op.
__global__ void gat_gather(const int* __restrict__ row_start, const int* __restrict__ csr_src,
                           const float* __restrict__ asrc, const float* __restrict__ adst,
                           const float* __restrict__ h, const float* __restrict__ bias,
                           float* __restrict__ out) {
    const int n = blockIdx.x * 4 + (threadIdx.x >> 6);
    const int lane = threadIdx.x & 63;
    if (n >= NN) return;
    const int lo = row_start[n], hi = row_start[n + 1];
    const float adn = adst[n];
    float den = 0.f;                       // per-lane partial, reduced at end
    float2 acc0 = {0.f, 0.f}, acc1 = {0.f, 0.f};
    for (int base = lo; base < hi; base += 64) {
        const int cnt = min(64, hi - base);
        const int sv = (lane < cnt) ? csr_src[base + lane] : 0;
        float ev = 0.f;
        if (lane < cnt) {
            float sc = asrc[sv] + adn;
            sc = sc > 0.f ? sc : 0.2f * sc;
            ev = __expf(sc);
        }
        den += ev;
        int j = 0;
        for (; j + 2 <= cnt; j += 2) {
            const int   s0 = __shfl(sv, j),     s1 = __shfl(sv, j + 1);
            const float e0 = __shfl(ev, j);
            const float e1 = __shfl(ev, j + 1);
            const float2 h0 = *(const float2*)(h + (size_t)s0 * F + lane * 2);
            const float2 h1 = *(const float2*)(h + (size_t)s1 * F + lane * 2);
            acc0.x = fmaf(e0, h0.x, acc0.x); acc0.y = fmaf(e0, h0.y, acc0.y);
            acc1.x = fmaf(e1, h1.x, acc1.x); acc1.y = fmaf(e1, h1.y, acc1.y);
        }
        if (j < cnt) {
            const int   s0 = __shfl(sv, j);
            const float e0 = __shfl(ev, j);
            const float2 h0 = *(const float2*)(h + (size_t)s0 * F + lane * 2);
            acc0.x = fmaf(e0, h0.x, acc0.x); acc0.y = fmaf(e0, h0.y, acc0.y);
        }
    }
    for (int o = 32; o; o >>= 1) den += __shfl_xor(den, o);
    const float inv = 1.f / den;           // den > 0 (self loop)
    float v0 = (acc0.x + acc1.x) * inv + bias[lane * 2];
    float v1 = (acc0.y + acc1.y) * inv + bias[lane * 2 + 1];
    float2* o = (float2*)(out + (size_t)n * F + lane * 2);
    *o = make_float2(v0 > 0.f ? v0 : 0.f, v1 > 0.f ? v1 : 0.f);
}

__global__ void make_dinv(const int* __restrict__ row_start, float* __restrict__ dinv) {
    const int n = blockIdx.x * blockDim.x + threadIdx.x;
    if (n >= NN) return;
    dinv[n] = rsqrtf((float)(row_start[n + 1] - row_start[n]));
}

// ---- GCN gather + fused mean-pool/head partials into padded per-graph scratch.
// Per-block LDS merge: 4 consecutive nodes share a graph almost always ->
// ~1 atomic pair per block onto a graph-private 128 B line (no hotspot).
__global__ void gcn_gather_pool(const int* __restrict__ row_start, const int* __restrict__ csr_src,
                                const float* __restrict__ dinv, const float* __restrict__ h,
                                const float* __restrict__ bias, const int* __restrict__ batch,
                                const float* __restrict__ Wf, float* __restrict__ gscr) {
    __shared__ int   sg[4];
    __shared__ float sp0[4], sp1[4];
    const int wave = threadIdx.x >> 6;
    const int n = blockIdx.x * 4 + wave;
    const int lane = threadIdx.x & 63;
    if (threadIdx.x < 4) sg[threadIdx.x] = -1;
    float p0 = 0.f, p1 = 0.f;
    if (n < NN) {
        const int lo = row_start[n], hi = row_start[n + 1];
        const float dn = dinv[n];
        float2 acc0 = {0.f, 0.f}, acc1 = {0.f, 0.f};
        for (int base = lo; base < hi; base += 64) {
            const int cnt = min(64, hi - base);
            const int sv = (lane < cnt) ? csr_src[base + lane] : 0;
            const float wv = (lane < cnt) ? dinv[sv] : 0.f;
            int j = 0;
            for (; j + 2 <= cnt; j += 2) {
                const int   s0 = __shfl(sv, j),  s1 = __shfl(sv, j + 1);
                const float w0 = __shfl(wv, j);
                const float w1 = __shfl(wv, j + 1);
                const float2 h0 = *(const float2*)(h + (size_t)s0 * F + lane * 2);
                const float2 h1 = *(const float2*)(h + (size_t)s1 * F + lane * 2);
                acc0.x = fmaf(w0, h0.x, acc0.x); acc0.y = fmaf(w0, h0.y, acc0.y);
                acc1.x = fmaf(w1, h1.x, acc1.x); acc1.y = fmaf(w1, h1.y, acc1.y);
            }
            if (j < cnt) {
                const int   s0 = __shfl(sv, j);
                const float w0 = __shfl(wv, j);
                const float2 h0 = *(const float2*)(h + (size_t)s0 * F + lane * 2);
                acc0.x = fmaf(w0, h0.x, acc0.x); acc0.y = fmaf(w0, h0.y, acc0.y);
            }
        }
        float v0 = (acc0.x + acc1.x) * dn + bias[lane * 2];
        float v1 = (acc0.y + acc1.y) * dn + bias[lane * 2 + 1];
        v0 = v0 > 0.f ? v0 : 0.f;
        v1 = v1 > 0.f ? v1 : 0.f;
        // project to 2 classes; butterfly-reduce across the wave
        p0 = v0 * Wf[(lane * 2) * 2]     + v1 * Wf[(lane * 2 + 1) * 2];
        p1 = v0 * Wf[(lane * 2) * 2 + 1] + v1 * Wf[(lane * 2 + 1) * 2 + 1];
        for (int o = 32; o; o >>= 1) { p0 += __shfl_xor(p0, o); p1 += __shfl_xor(p1, o); }
    }
    if (lane == 0 && n < NN) { sg[wave] = batch[n]; sp0[wave] = p0; sp1[wave] = p1; }
    __syncthreads();
    if (threadIdx.x == 0) {
#pragma unroll
        for (int w = 0; w < 4; ++w) {
            const int g = sg[w];
            if (g < 0) continue;
            float q0 = sp0[w], q1 = sp1[w];
            for (int u = w + 1; u < 4; ++u) {
                if (sg[u] == g) { q0 += sp0[u]; q1 += sp1[u]; sg[u] = -1; }
            }
            atomicAdd(gscr + g * 32,     q0);
            atomicAdd(gscr + g * 32 + 1, q1);
        }
    }
}

// out[g,c] = gscr[g*32+c] / cnt_g + bf[c]; cnt via binary search on sorted batch
__global__ void finalize(const float* __restrict__ gscr, const int* __restrict__ batch,
                         const float* __restrict__ bf, float* __restrict__ out) {
    const int g = threadIdx.x;   // 128
    int lo = 0, hi = NN;
    while (lo < hi) { int m = (lo + hi) >> 1; if (batch[m] < g) lo = m + 1; else hi = m; }
    int lo2 = lo, hi2 = NN;
    while (lo2 < hi2) { int m = (lo2 + hi2) >> 1; if (batch[m] < g + 1) lo2 = m + 1; else hi2 = m; }
    const float inv = 1.f / fmaxf((float)(lo2 - lo), 1.f);
    out[g * 2]     = gscr[g * 32]     * inv + bf[0];
    out[g * 2 + 1] = gscr[g * 32 + 1] * inv + bf[1];
}

extern "C" void kernel_launch(void* const* d_in, const int* in_sizes, int n_in,
                              void* d_out, int out_size, void* d_ws, size_t ws_size,
                              hipStream_t stream) {
    const float* x       = (const float*)d_in[0];
    const float* W1      = (const float*)d_in[1];
    const float* att_src = (const float*)d_in[2];
    const float* att_dst = (const float*)d_in[3];
    const float* b1      = (const float*)d_in[4];
    const float* W2      = (const float*)d_in[5];
    const float* b2      = (const float*)d_in[6];
    const float* Wf      = (const float*)d_in[7];
    const float* bf      = (const float*)d_in[8];
    const int*   ei      = (const int*)d_in[9];
    const int*   batch   = (const int*)d_in[10];
    float* out = (float*)d_out;

    float* ws        = (float*)d_ws;
    float* h1        = ws;                       // [NN*F]
    float* hg        = h1 + (size_t)NN * F;      // [NN*F]
    float* h2        = hg + (size_t)NN * F;      // [NN*F]
    float* asrc      = h2 + (size_t)NN * F;      // [NN]
    float* adst      = asrc + NN;                // [NN]
    float* dinv      = adst + NN;                // [NN]
    float* gscr      = dinv + NN;                // [NG*32] padded per-graph partials
    int*   deg       = (int*)(gscr + NG * 32);   // [NN] histogram, then scatter cursor
    int*   row_start = deg + NN;                 // [NN+1]
    int*   csr_src   = row_start + NN + 1;       // [EP]

    // CSR build (independent of feature path)
    hipMemsetAsync(deg, 0, NN * sizeof(int), stream);
    hipMemsetAsync(gscr, 0, NG * 32 * sizeof(float), stream);
    hist_deg<<<(EP + 255) / 256, 256, 0, stream>>>(ei, deg);
    scan_rows<<<1, 1024, 0, stream>>>(deg, row_start);
    hipMemsetAsync(deg, 0, NN * sizeof(int), stream);
    scatter_csr<<<(EP + 255) / 256, 256, 0, stream>>>(ei, row_start, deg, csr_src);

    gemm_tiled<<<(NN + 127) / 128, 256, 0, stream>>>(x, W1, h1, NN);
    node_scores<<<(NN + 3) / 4, 256, 0, stream>>>(h1, att_src, att_dst, asrc, adst, NN);
    gat_gather<<<(NN + 3) / 4, 256, 0, stream>>>(row_start, csr_src, asrc, adst, h1, b1, hg);
    gemm_tiled<<<(NN + 127) / 128, 256, 0, stream>>>(hg, W2, h2, NN);
    make_dinv<<<(NN + 255) / 256, 256, 0, stream>>>(row_start, dinv);
    gcn_gather_pool<<<(NN + 3) / 4, 256, 0, stream>>>(row_start, csr_src, dinv, h2, b2,
                                                      batch, Wf, gscr);
    finalize<<<1, NG, 0, stream>>>(gscr, batch, bf, out);
}

// Round 7
// 405.128 us; speedup vs baseline: 2.1224x; 1.1569x over previous
//
#include <hip/hip_runtime.h>

#define NN 50000
#define NE 800000
#define EP (NE + NN)      // edges + self loops = 850000
#define NG 128
#define F 128
#define SW 140            // Ws row stride (floats), fits swizzle range [0,140)
// injective W column swizzle: c + 4*(c/32). 16 col-groups -> all banks at 2-way (free).
#define SWZ(c) ((c) + (((c) >> 5) << 2))
#define NB_SCAN ((NN + 255) / 256)   // 196

__device__ inline void fma4(float4& a, float s, const float4& b) {
    a.x = fmaf(s, b.x, a.x); a.y = fmaf(s, b.y, a.y);
    a.z = fmaf(s, b.z, a.z); a.w = fmaf(s, b.w, a.w);
}

// C[N,128] = A[N,128] @ W[128,128], fp32. Block tile 128x128, thread tile 8x8.
// Optional fused epilogue: asrc[n]=C[n,:]@att_src, adst[n]=C[n,:]@att_dst
// (reduced from accumulator registers across the 16 threads sharing each row).
__global__ __launch_bounds__(256, 1) void gemm_tiled(const float* __restrict__ A,
                                                     const float* __restrict__ W,
                                                     float* __restrict__ C, int N,
                                                     const float* __restrict__ att_src,
                                                     const float* __restrict__ att_dst,
                                                     float* __restrict__ asrc,
                                                     float* __restrict__ adst) {
    __shared__ float As[128 * 128];   // [row][(k+rot)&127]
    __shared__ float Ws[128 * SW];    // [k][SWZ(col)]
    const int tid = threadIdx.x;
    const int row0 = blockIdx.x * 128;
#pragma unroll
    for (int i = 0; i < 16; ++i) {
        const int idx = i * 256 + tid;          // 0..4095
        const int r = idx >> 5;                 // k-row for W, node-row for A
        const int c4 = (idx & 31) << 2;
        const float4 wv = *(const float4*)(W + r * F + c4);
        *(float4*)(Ws + r * SW + SWZ(c4)) = wv;
        const int gr = row0 + r;
        const float4 av = (gr < N) ? *(const float4*)(A + (size_t)gr * F + c4)
                                   : make_float4(0.f, 0.f, 0.f, 0.f);
        *(float4*)(As + r * 128 + ((c4 + 8 * ((r >> 3) & 3)) & 127)) = av;
    }
    __syncthreads();
    const int rg = tid >> 4, cg = tid & 15;
    const int r0 = rg * 8, c0 = cg * 8;
    const int rot_a = 8 * (rg & 3);
    const int co0 = SWZ(c0);
    const int co1 = SWZ(c0 + 4);
    float4 acc[8][2] = {};
    for (int k4 = 0; k4 < F; k4 += 4) {
        const int ka = (k4 + rot_a) & 127;
        float4 a[8];
#pragma unroll
        for (int r = 0; r < 8; ++r) a[r] = *(const float4*)(As + (r0 + r) * 128 + ka);
#pragma unroll
        for (int j = 0; j < 4; ++j) {
            const float4 w0 = *(const float4*)(Ws + (k4 + j) * SW + co0);
            const float4 w1 = *(const float4*)(Ws + (k4 + j) * SW + co1);
#pragma unroll
            for (int r = 0; r < 8; ++r) {
                const float aj = ((const float*)&a[r])[j];
                fma4(acc[r][0], aj, w0);
                fma4(acc[r][1], aj, w1);
            }
        }
    }
#pragma unroll
    for (int r = 0; r < 8; ++r) {
        const int gr = row0 + r0 + r;
        if (gr < N) {
            *(float4*)(C + (size_t)gr * F + c0) = acc[r][0];
            *(float4*)(C + (size_t)gr * F + c0 + 4) = acc[r][1];
        }
    }
    if (asrc) {   // fused attention-score epilogue (gemm1 only)
        const float4 sa0 = *(const float4*)(att_src + c0);
        const float4 sa1 = *(const float4*)(att_src + c0 + 4);
        const float4 da0 = *(const float4*)(att_dst + c0);
        const float4 da1 = *(const float4*)(att_dst + c0 + 4);
#pragma unroll
        for (int r = 0; r < 8; ++r) {
            float ps = acc[r][0].x * sa0.x + acc[r][0].y * sa0.y + acc[r][0].z * sa0.z +
                       acc[r][0].w * sa0.w + acc[r][1].x * sa1.x + acc[r][1].y * sa1.y +
                       acc[r][1].z * sa1.z + acc[r][1].w * sa1.w;
            float pd = acc[r][0].x * da0.x + acc[r][0].y * da0.y + acc[r][0].z * da0.z +
                       acc[r][0].w * da0.w + acc[r][1].x * da1.x + acc[r][1].y * da1.y +
                       acc[r][1].z * da1.z + acc[r][1].w * da1.w;
#pragma unroll
            for (int o = 8; o; o >>= 1) { ps += __shfl_xor(ps, o); pd += __shfl_xor(pd, o); }
            if (cg == 0) {
                const int gr = row0 + r0 + r;
                if (gr < N) { asrc[gr] = ps; adst[gr] = pd; }
            }
        }
    }
}

// ---- CSR build: histogram -> hierarchical scan -> scatter ----
__global__ void hist_deg(const int* __restrict__ ei, int* __restrict__ deg) {
    const int e = blockIdx.x * blockDim.x + threadIdx.x;
    if (e >= EP) return;
    const int d = (e < NE) ? ei[NE + e] : e - NE;
    atomicAdd(deg + d, 1);
}

// per-block exclusive scan of 256 deg values; block total to bsum
__global__ void scan_blk(const int* __restrict__ deg, int* __restrict__ rs,
                         int* __restrict__ bsum) {
    __shared__ int sh[256];
    const int t = threadIdx.x;
    const int i = blockIdx.x * 256 + t;
    const int v = (i < NN) ? deg[i] : 0;
    sh[t] = v;
    __syncthreads();
    for (int o = 1; o < 256; o <<= 1) {
        const int u = (t >= o) ? sh[t - o] : 0;
        __syncthreads();
        sh[t] += u;
        __syncthreads();
    }
    if (i < NN) rs[i] = sh[t] - v;
    if (t == 255) bsum[blockIdx.x] = sh[255];
}

// exclusive scan of the 196 block sums
__global__ void scan_top(const int* __restrict__ bsum, int* __restrict__ boff) {
    __shared__ int sh[256];
    const int t = threadIdx.x;
    const int v = (t < NB_SCAN) ? bsum[t] : 0;
    sh[t] = v;
    __syncthreads();
    for (int o = 1; o < 256; o <<= 1) {
        const int u = (t >= o) ? sh[t - o] : 0;
        __syncthreads();
        sh[t] += u;
        __syncthreads();
    }
    if (t < NB_SCAN) boff[t] = sh[t] - v;
}

__global__ void scan_add(int* __restrict__ rs, const int* __restrict__ boff) {
    const int i = blockIdx.x * 256 + threadIdx.x;
    if (i < NN) rs[i] += boff[blockIdx.x];
    if (i == 0) rs[NN] = EP;   // total is statically known
}

__global__ void scatter_csr(const int* __restrict__ ei, const int* __restrict__ row_start,
                            int* __restrict__ cnt, int* __restrict__ csr_src) {
    const int e = blockIdx.x * blockDim.x + threadIdx.x;
    if (e >= EP) return;
    int s, d;
    if (e < NE) { s = ei[e]; d = ei[NE + e]; } else { s = d = e - NE; }
    const int pos = row_start[d] + atomicAdd(cnt + d, 1);
    csr_src[pos] = s;
}

// ---- GAT gather: one wave per dst node. Indices+exp-weights prefetched 64-wide;
// the two 32-lane halves each load a DIFFERENT edge's row as float4 (16B/lane),
// 2x unrolled -> 4 edges / 2 loads per lane in flight; halves merged via xor-32.
__global__ void gat_gather(const int* __restrict__ row_start, const int* __restrict__ csr_src,
                           const float* __restrict__ asrc, const float* __restrict__ adst,
                           const float* __restrict__ h, const float* __restrict__ bias,
                           float* __restrict__ out) {
    const int n = blockIdx.x * 4 + (threadIdx.x >> 6);
    const int lane = threadIdx.x & 63;
    if (n >= NN) return;
    const int half = lane >> 5;
    const int q = (lane & 31) << 2;   // feature quad
    const int lo = row_start[n], hi = row_start[n + 1];
    const float adn = adst[n];
    float den = 0.f;
    float4 accA = {0.f, 0.f, 0.f, 0.f}, accB = {0.f, 0.f, 0.f, 0.f};
    for (int base = lo; base < hi; base += 64) {
        const int cnt = min(64, hi - base);
        const int sv = (lane < cnt) ? csr_src[base + lane] : 0;
        float ev = 0.f;
        if (lane < cnt) {
            float sc = asrc[sv] + adn;
            sc = sc > 0.f ? sc : 0.2f * sc;
            ev = __expf(sc);
        }
        den += ev;                 // lanes >= cnt contribute 0
        int j = 0;
        for (; j + 4 <= cnt; j += 4) {
            const int   sA = __shfl(sv, j + half);
            const float eA = __shfl(ev, j + half);
            const int   sB = __shfl(sv, j + 2 + half);
            const float eB = __shfl(ev, j + 2 + half);
            const float4 hA = *(const float4*)(h + (size_t)sA * F + q);
            const float4 hB = *(const float4*)(h + (size_t)sB * F + q);
            fma4(accA, eA, hA);
            fma4(accB, eB, hB);
        }
        for (; j < cnt; j += 2) {
            const int jj = j + half;     // jj<=cnt: lane cnt (if hit) has ev=0, sv=0 valid
            const int   sA = __shfl(sv, jj);
            const float eA = __shfl(ev, jj);
            const float4 hA = *(const float4*)(h + (size_t)sA * F + q);
            fma4(accA, eA, hA);
        }
    }
    float4 acc = make_float4(accA.x + accB.x, accA.y + accB.y,
                             accA.z + accB.z, accA.w + accB.w);
    acc.x += __shfl_xor(acc.x, 32); acc.y += __shfl_xor(acc.y, 32);
    acc.z += __shfl_xor(acc.z, 32); acc.w += __shfl_xor(acc.w, 32);
    for (int o = 32; o; o >>= 1) den += __shfl_xor(den, o);
    const float inv = 1.f / den;       // den > 0 (self loop)
    if (half == 0) {
        const float4 b4 = *(const float4*)(bias + q);
        float4 v;
        v.x = fmaf(acc.x, inv, b4.x); v.y = fmaf(acc.y, inv, b4.y);
        v.z = fmaf(acc.z, inv, b4.z); v.w = fmaf(acc.w, inv, b4.w);
        v.x = v.x > 0.f ? v.x : 0.f;  v.y = v.y > 0.f ? v.y : 0.f;
        v.z = v.z > 0.f ? v.z : 0.f;  v.w = v.w > 0.f ? v.w : 0.f;
        *(float4*)(out + (size_t)n * F + q) = v;
    }
}

__global__ void make_dinv(const int* __restrict__ row_start, float* __restrict__ dinv) {
    const int n = blockIdx.x * blockDim.x + threadIdx.x;
    if (n >= NN) return;
    dinv[n] = rsqrtf((float)(row_start[n + 1] - row_start[n]));
}

// ---- GCN gather + fused mean-pool/head partials into padded per-graph scratch.
__global__ void gcn_gather_pool(const int* __restrict__ row_start, const int* __restrict__ csr_src,
                                const float* __restrict__ dinv, const float* __restrict__ h,
                                const float* __restrict__ bias, const int* __restrict__ batch,
                                const float* __restrict__ Wf, float* __restrict__ gscr) {
    __shared__ int   sg[4];
    __shared__ float sp0[4], sp1[4];
    const int wave = threadIdx.x >> 6;
    const int n = blockIdx.x * 4 + wave;
    const int lane = threadIdx.x & 63;
    const int half = lane >> 5;
    const int q = (lane & 31) << 2;
    if (threadIdx.x < 4) sg[threadIdx.x] = -1;
    float p0 = 0.f, p1 = 0.f;
    if (n < NN) {
        const int lo = row_start[n], hi = row_start[n + 1];
        const float dn = dinv[n];
        float4 accA = {0.f, 0.f, 0.f, 0.f}, accB = {0.f, 0.f, 0.f, 0.f};
        for (int base = lo; base < hi; base += 64) {
            const int cnt = min(64, hi - base);
            const int sv = (lane < cnt) ? csr_src[base + lane] : 0;
            const float wv = (lane < cnt) ? dinv[sv] : 0.f;
            int j = 0;
            for (; j + 4 <= cnt; j += 4) {
                const int   sA = __shfl(sv, j + half);
                const float wA = __shfl(wv, j + half);
                const int   sB = __shfl(sv, j + 2 + half);
                const float wB = __shfl(wv, j + 2 + half);
                const float4 hA = *(const float4*)(h + (size_t)sA * F + q);
                const float4 hB = *(const float4*)(h + (size_t)sB * F + q);
                fma4(accA, wA, hA);
                fma4(accB, wB, hB);
            }
            for (; j < cnt; j += 2) {
                const int jj = j + half;
                const int   sA = __shfl(sv, jj);
                const float wA = __shfl(wv, jj);
                const float4 hA = *(const float4*)(h + (size_t)sA * F + q);
                fma4(accA, wA, hA);
            }
        }
        float4 acc = make_float4(accA.x + accB.x, accA.y + accB.y,
                                 accA.z + accB.z, accA.w + accB.w);
        acc.x += __shfl_xor(acc.x, 32); acc.y += __shfl_xor(acc.y, 32);
        acc.z += __shfl_xor(acc.z, 32); acc.w += __shfl_xor(acc.w, 32);
        const float4 b4 = *(const float4*)(bias + q);
        float v0 = fmaf(acc.x, dn, b4.x), v1 = fmaf(acc.y, dn, b4.y);
        float v2 = fmaf(acc.z, dn, b4.z), v3 = fmaf(acc.w, dn, b4.w);
        v0 = v0 > 0.f ? v0 : 0.f; v1 = v1 > 0.f ? v1 : 0.f;
        v2 = v2 > 0.f ? v2 : 0.f; v3 = v3 > 0.f ? v3 : 0.f;
        // project to 2 classes: Wf rows q..q+3, interleaved [c][2]
        const float4 wfa = *(const float4*)(Wf + q * 2);       // W[q][0..1], W[q+1][0..1]
        const float4 wfb = *(const float4*)(Wf + q * 2 + 4);   // W[q+2][0..1], W[q+3][0..1]
        p0 = v0 * wfa.x + v1 * wfa.z + v2 * wfb.x + v3 * wfb.z;
        p1 = v0 * wfa.y + v1 * wfa.w + v2 * wfb.y + v3 * wfb.w;
        // reduce within each 32-lane half (halves hold identical totals)
        for (int o = 16; o; o >>= 1) { p0 += __shfl_xor(p0, o); p1 += __shfl_xor(p1, o); }
    }
    if (lane == 0 && n < NN) { sg[wave] = batch[n]; sp0[wave] = p0; sp1[wave] = p1; }
    __syncthreads();
    if (threadIdx.x == 0) {
#pragma unroll
        for (int w = 0; w < 4; ++w) {
            const int g = sg[w];
            if (g < 0) continue;
            float q0 = sp0[w], q1 = sp1[w];
            for (int u = w + 1; u < 4; ++u) {
                if (sg[u] == g) { q0 += sp0[u]; q1 += sp1[u]; sg[u] = -1; }
            }
            atomicAdd(gscr + g * 32,     q0);
            atomicAdd(gscr + g * 32 + 1, q1);
        }
    }
}

// out[g,c] = gscr[g*32+c] / cnt_g + bf[c]; cnt via binary search on sorted batch
__global__ void finalize(const float* __restrict__ gscr, const int* __restrict__ batch,
                         const float* __restrict__ bf, float* __restrict__ out) {
    const int g = threadIdx.x;   // 128
    int lo = 0, hi = NN;
    while (lo < hi) { int m = (lo + hi) >> 1; if (batch[m] < g) lo = m + 1; else hi = m; }
    int lo2 = lo, hi2 = NN;
    while (lo2 < hi2) { int m = (lo2 + hi2) >> 1; if (batch[m] < g + 1) lo2 = m + 1; else hi2 = m; }
    const float inv = 1.f / fmaxf((float)(lo2 - lo), 1.f);
    out[g * 2]     = gscr[g * 32]     * inv + bf[0];
    out[g * 2 + 1] = gscr[g * 32 + 1] * inv + bf[1];
}

extern "C" void kernel_launch(void* const* d_in, const int* in_sizes, int n_in,
                              void* d_out, int out_size, void* d_ws, size_t ws_size,
                              hipStream_t stream) {
    const float* x       = (const float*)d_in[0];
    const float* W1      = (const float*)d_in[1];
    const float* att_src = (const float*)d_in[2];
    const float* att_dst = (const float*)d_in[3];
    const float* b1      = (const float*)d_in[4];
    const float* W2      = (const float*)d_in[5];
    const float* b2      = (const float*)d_in[6];
    const float* Wf      = (const float*)d_in[7];
    const float* bf      = (const float*)d_in[8];
    const int*   ei      = (const int*)d_in[9];
    const int*   batch   = (const int*)d_in[10];
    float* out = (float*)d_out;

    float* ws        = (float*)d_ws;
    float* h1        = ws;                       // [NN*F]
    float* hg        = h1 + (size_t)NN * F;      // [NN*F]
    float* h2        = hg + (size_t)NN * F;      // [NN*F]
    float* asrc      = h2 + (size_t)NN * F;      // [NN]
    float* adst      = asrc + NN;                // [NN]
    float* dinv      = adst + NN;                // [NN]
    float* gscr      = dinv + NN;                // [NG*32] padded per-graph partials
    int*   deg       = (int*)(gscr + NG * 32);   // [NN] histogram, then scatter cursor
    int*   row_start = deg + NN;                 // [NN+1]
    int*   csr_src   = row_start + NN + 1;       // [EP]
    int*   bsum      = csr_src + EP;             // [256]
    int*   boff      = bsum + 256;               // [256]

    // CSR build (independent of feature path)
    hipMemsetAsync(deg, 0, NN * sizeof(int), stream);
    hipMemsetAsync(gscr, 0, NG * 32 * sizeof(float), stream);
    hist_deg<<<(EP + 255) / 256, 256, 0, stream>>>(ei, deg);
    scan_blk<<<NB_SCAN, 256, 0, stream>>>(deg, row_start, bsum);
    scan_top<<<1, 256, 0, stream>>>(bsum, boff);
    scan_add<<<NB_SCAN, 256, 0, stream>>>(row_start, boff);
    hipMemsetAsync(deg, 0, NN * sizeof(int), stream);
    scatter_csr<<<(EP + 255) / 256, 256, 0, stream>>>(ei, row_start, deg, csr_src);

    gemm_tiled<<<(NN + 127) / 128, 256, 0, stream>>>(x, W1, h1, NN,
                                                     att_src, att_dst, asrc, adst);
    gat_gather<<<(NN + 3) / 4, 256, 0, stream>>>(row_start, csr_src, asrc, adst, h1, b1, hg);
    gemm_tiled<<<(NN + 127) / 128, 256, 0, stream>>>(hg, W2, h2, NN,
                                                     nullptr, nullptr, nullptr, nullptr);
    make_dinv<<<(NN + 255) / 256, 256, 0, stream>>>(row_start, dinv);
    gcn_gather_pool<<<(NN + 3) / 4, 256, 0, stream>>>(row_start, csr_src, dinv, h2, b2,
                                                      batch, Wf, gscr);
    finalize<<<1, NG, 0, stream>>>(gscr, batch, bf, out);
}

// Round 8
// 369.137 us; speedup vs baseline: 2.3294x; 1.0975x over previous
//
#include <hip/hip_runtime.h>

#define NN 50000
#define NE 800000
#define EP (NE + NN)      // edges + self loops = 850000
#define NG 128
#define F 128
#define SW 140            // Ws row stride (floats), fits swizzle range [0,140)
// injective W column swizzle: c + 4*(c/32). 16 col-groups -> all banks at 2-way (free).
#define SWZ(c) ((c) + (((c) >> 5) << 2))
#define NB_SCAN ((NN + 255) / 256)   // 196

__device__ inline void fma4(float4& a, float s, const float4& b) {
    a.x = fmaf(s, b.x, a.x); a.y = fmaf(s, b.y, a.y);
    a.z = fmaf(s, b.z, a.z); a.w = fmaf(s, b.w, a.w);
}

// C[N,128] = A[N,128] @ W[128,128], fp32. Block tile 128x128, 512 threads,
// thread tile 4x8 -> 8 waves/CU (2/SIMD) so LDS latency overlaps compute.
// Optional fused epilogue: asrc[n]=C[n,:]@att_src, adst[n]=C[n,:]@att_dst.
__global__ __launch_bounds__(512, 1) void gemm_tiled(const float* __restrict__ A,
                                                     const float* __restrict__ W,
                                                     float* __restrict__ C, int N,
                                                     const float* __restrict__ att_src,
                                                     const float* __restrict__ att_dst,
                                                     float* __restrict__ asrc,
                                                     float* __restrict__ adst) {
    __shared__ float As[128 * 128];   // [row][(k+rot)&127], rot = 8*((row>>3)&3)
    __shared__ float Ws[128 * SW];    // [k][SWZ(col)]
    const int tid = threadIdx.x;
    const int row0 = blockIdx.x * 128;
#pragma unroll
    for (int i = 0; i < 8; ++i) {
        const int idx = i * 512 + tid;          // 0..4095
        const int r = idx >> 5;                 // k-row for W, node-row for A
        const int c4 = (idx & 31) << 2;
        const float4 wv = *(const float4*)(W + r * F + c4);
        *(float4*)(Ws + r * SW + SWZ(c4)) = wv;
        const int gr = row0 + r;
        const float4 av = (gr < N) ? *(const float4*)(A + (size_t)gr * F + c4)
                                   : make_float4(0.f, 0.f, 0.f, 0.f);
        *(float4*)(As + r * 128 + ((c4 + 8 * ((r >> 3) & 3)) & 127)) = av;
    }
    __syncthreads();
    const int rg = tid >> 4, cg = tid & 15;     // rg 0..31, cg 0..15
    const int r0 = rg * 4, c0 = cg * 8;
    const int rot_a = 8 * ((rg >> 1) & 3);      // rows r0..r0+3 share (row>>3)&3
    const int co0 = SWZ(c0);
    const int co1 = SWZ(c0 + 4);
    float4 acc[4][2] = {};
    for (int k4 = 0; k4 < F; k4 += 4) {
        const int ka = (k4 + rot_a) & 127;
        float4 a[4];
#pragma unroll
        for (int r = 0; r < 4; ++r) a[r] = *(const float4*)(As + (r0 + r) * 128 + ka);
#pragma unroll
        for (int j = 0; j < 4; ++j) {
            const float4 w0 = *(const float4*)(Ws + (k4 + j) * SW + co0);
            const float4 w1 = *(const float4*)(Ws + (k4 + j) * SW + co1);
#pragma unroll
            for (int r = 0; r < 4; ++r) {
                const float aj = ((const float*)&a[r])[j];
                fma4(acc[r][0], aj, w0);
                fma4(acc[r][1], aj, w1);
            }
        }
    }
#pragma unroll
    for (int r = 0; r < 4; ++r) {
        const int gr = row0 + r0 + r;
        if (gr < N) {
            *(float4*)(C + (size_t)gr * F + c0) = acc[r][0];
            *(float4*)(C + (size_t)gr * F + c0 + 4) = acc[r][1];
        }
    }
    if (asrc) {   // fused attention-score epilogue (gemm1 only)
        const float4 sa0 = *(const float4*)(att_src + c0);
        const float4 sa1 = *(const float4*)(att_src + c0 + 4);
        const float4 da0 = *(const float4*)(att_dst + c0);
        const float4 da1 = *(const float4*)(att_dst + c0 + 4);
#pragma unroll
        for (int r = 0; r < 4; ++r) {
            float ps = acc[r][0].x * sa0.x + acc[r][0].y * sa0.y + acc[r][0].z * sa0.z +
                       acc[r][0].w * sa0.w + acc[r][1].x * sa1.x + acc[r][1].y * sa1.y +
                       acc[r][1].z * sa1.z + acc[r][1].w * sa1.w;
            float pd = acc[r][0].x * da0.x + acc[r][0].y * da0.y + acc[r][0].z * da0.z +
                       acc[r][0].w * da0.w + acc[r][1].x * da1.x + acc[r][1].y * da1.y +
                       acc[r][1].z * da1.z + acc[r][1].w * da1.w;
#pragma unroll
            for (int o = 8; o; o >>= 1) { ps += __shfl_xor(ps, o); pd += __shfl_xor(pd, o); }
            if (cg == 0) {
                const int gr = row0 + r0 + r;
                if (gr < N) { asrc[gr] = ps; adst[gr] = pd; }
            }
        }
    }
}

// ---- CSR build: histogram -> hierarchical scan -> scatter ----
__global__ void hist_deg(const int* __restrict__ ei, int* __restrict__ deg) {
    const int e = blockIdx.x * blockDim.x + threadIdx.x;
    if (e >= EP) return;
    const int d = (e < NE) ? ei[NE + e] : e - NE;
    atomicAdd(deg + d, 1);
}

__global__ void scan_blk(const int* __restrict__ deg, int* __restrict__ rs,
                         int* __restrict__ bsum) {
    __shared__ int sh[256];
    const int t = threadIdx.x;
    const int i = blockIdx.x * 256 + t;
    const int v = (i < NN) ? deg[i] : 0;
    sh[t] = v;
    __syncthreads();
    for (int o = 1; o < 256; o <<= 1) {
        const int u = (t >= o) ? sh[t - o] : 0;
        __syncthreads();
        sh[t] += u;
        __syncthreads();
    }
    if (i < NN) rs[i] = sh[t] - v;
    if (t == 255) bsum[blockIdx.x] = sh[255];
}

__global__ void scan_top(const int* __restrict__ bsum, int* __restrict__ boff) {
    __shared__ int sh[256];
    const int t = threadIdx.x;
    const int v = (t < NB_SCAN) ? bsum[t] : 0;
    sh[t] = v;
    __syncthreads();
    for (int o = 1; o < 256; o <<= 1) {
        const int u = (t >= o) ? sh[t - o] : 0;
        __syncthreads();
        sh[t] += u;
        __syncthreads();
    }
    if (t < NB_SCAN) boff[t] = sh[t] - v;
}

__global__ void scan_add(int* __restrict__ rs, const int* __restrict__ boff) {
    const int i = blockIdx.x * 256 + threadIdx.x;
    if (i < NN) rs[i] += boff[blockIdx.x];
    if (i == 0) rs[NN] = EP;   // total is statically known
}

__global__ void scatter_csr(const int* __restrict__ ei, const int* __restrict__ row_start,
                            int* __restrict__ cnt, int* __restrict__ csr_src) {
    const int e = blockIdx.x * blockDim.x + threadIdx.x;
    if (e >= EP) return;
    int s, d;
    if (e < NE) { s = ei[e]; d = ei[NE + e]; } else { s = d = e - NE; }
    const int pos = row_start[d] + atomicAdd(cnt + d, 1);
    csr_src[pos] = s;
}

// ---- GAT gather: one wave per dst node. Indices+exp-weights prefetched 64-wide;
// two 32-lane halves each stream different edges' rows as float4 (16B/lane),
// 4 edges per half in flight (4 independent accumulators) for MLP depth.
__global__ void gat_gather(const int* __restrict__ row_start, const int* __restrict__ csr_src,
                           const float* __restrict__ asrc, const float* __restrict__ adst,
                           const float* __restrict__ h, const float* __restrict__ bias,
                           float* __restrict__ out) {
    const int n = blockIdx.x * 4 + (threadIdx.x >> 6);
    const int lane = threadIdx.x & 63;
    if (n >= NN) return;
    const int half = lane >> 5;
    const int q = (lane & 31) << 2;   // feature quad
    const int lo = row_start[n], hi = row_start[n + 1];
    const float adn = adst[n];
    float den = 0.f;
    float4 accA = {0,0,0,0}, accB = {0,0,0,0}, accC = {0,0,0,0}, accD = {0,0,0,0};
    for (int base = lo; base < hi; base += 64) {
        const int cnt = min(64, hi - base);
        const int sv = (lane < cnt) ? csr_src[base + lane] : 0;
        float ev = 0.f;
        if (lane < cnt) {
            float sc = asrc[sv] + adn;
            sc = sc > 0.f ? sc : 0.2f * sc;
            ev = __expf(sc);
        }
        den += ev;                 // lanes >= cnt contribute 0
        int j = 0;
        for (; j + 8 <= cnt; j += 8) {
            const int   s0 = __shfl(sv, j + half),     s1 = __shfl(sv, j + 2 + half);
            const int   s2 = __shfl(sv, j + 4 + half), s3 = __shfl(sv, j + 6 + half);
            const float e0 = __shfl(ev, j + half),     e1 = __shfl(ev, j + 2 + half);
            const float e2 = __shfl(ev, j + 4 + half), e3 = __shfl(ev, j + 6 + half);
            const float4 h0 = *(const float4*)(h + (size_t)s0 * F + q);
            const float4 h1 = *(const float4*)(h + (size_t)s1 * F + q);
            const float4 h2 = *(const float4*)(h + (size_t)s2 * F + q);
            const float4 h3 = *(const float4*)(h + (size_t)s3 * F + q);
            fma4(accA, e0, h0); fma4(accB, e1, h1);
            fma4(accC, e2, h2); fma4(accD, e3, h3);
        }
        for (; j + 4 <= cnt; j += 4) {
            const int   s0 = __shfl(sv, j + half),  s1 = __shfl(sv, j + 2 + half);
            const float e0 = __shfl(ev, j + half);
            const float e1 = __shfl(ev, j + 2 + half);
            const float4 h0 = *(const float4*)(h + (size_t)s0 * F + q);
            const float4 h1 = *(const float4*)(h + (size_t)s1 * F + q);
            fma4(accA, e0, h0); fma4(accB, e1, h1);
        }
        for (; j < cnt; j += 2) {
            const int jj = j + half;     // lane cnt (if hit) has ev=0, sv=0 valid
            const int   s0 = __shfl(sv, jj);
            const float e0 = __shfl(ev, jj);
            const float4 h0 = *(const float4*)(h + (size_t)s0 * F + q);
            fma4(accA, e0, h0);
        }
    }
    float4 acc = make_float4(accA.x + accB.x + accC.x + accD.x,
                             accA.y + accB.y + accC.y + accD.y,
                             accA.z + accB.z + accC.z + accD.z,
                             accA.w + accB.w + accC.w + accD.w);
    acc.x += __shfl_xor(acc.x, 32); acc.y += __shfl_xor(acc.y, 32);
    acc.z += __shfl_xor(acc.z, 32); acc.w += __shfl_xor(acc.w, 32);
    for (int o = 32; o; o >>= 1) den += __shfl_xor(den, o);
    const float inv = 1.f / den;       // den > 0 (self loop)
    if (half == 0) {
        const float4 b4 = *(const float4*)(bias + q);
        float4 v;
        v.x = fmaf(acc.x, inv, b4.x); v.y = fmaf(acc.y, inv, b4.y);
        v.z = fmaf(acc.z, inv, b4.z); v.w = fmaf(acc.w, inv, b4.w);
        v.x = v.x > 0.f ? v.x : 0.f;  v.y = v.y > 0.f ? v.y : 0.f;
        v.z = v.z > 0.f ? v.z : 0.f;  v.w = v.w > 0.f ? v.w : 0.f;
        *(float4*)(out + (size_t)n * F + q) = v;
    }
}

__global__ void make_dinv(const int* __restrict__ row_start, float* __restrict__ dinv) {
    const int n = blockIdx.x * blockDim.x + threadIdx.x;
    if (n >= NN) return;
    dinv[n] = rsqrtf((float)(row_start[n + 1] - row_start[n]));
}

// ---- GCN gather + fused mean-pool/head partials into padded per-graph scratch.
__global__ void gcn_gather_pool(const int* __restrict__ row_start, const int* __restrict__ csr_src,
                                const float* __restrict__ dinv, const float* __restrict__ h,
                                const float* __restrict__ bias, const int* __restrict__ batch,
                                const float* __restrict__ Wf, float* __restrict__ gscr) {
    __shared__ int   sg[4];
    __shared__ float sp0[4], sp1[4];
    const int wave = threadIdx.x >> 6;
    const int n = blockIdx.x * 4 + wave;
    const int lane = threadIdx.x & 63;
    const int half = lane >> 5;
    const int q = (lane & 31) << 2;
    if (threadIdx.x < 4) sg[threadIdx.x] = -1;
    float p0 = 0.f, p1 = 0.f;
    if (n < NN) {
        const int lo = row_start[n], hi = row_start[n + 1];
        const float dn = dinv[n];
        float4 accA = {0,0,0,0}, accB = {0,0,0,0}, accC = {0,0,0,0}, accD = {0,0,0,0};
        for (int base = lo; base < hi; base += 64) {
            const int cnt = min(64, hi - base);
            const int sv = (lane < cnt) ? csr_src[base + lane] : 0;
            const float wv = (lane < cnt) ? dinv[sv] : 0.f;
            int j = 0;
            for (; j + 8 <= cnt; j += 8) {
                const int   s0 = __shfl(sv, j + half),     s1 = __shfl(sv, j + 2 + half);
                const int   s2 = __shfl(sv, j + 4 + half), s3 = __shfl(sv, j + 6 + half);
                const float w0 = __shfl(wv, j + half),     w1 = __shfl(wv, j + 2 + half);
                const float w2 = __shfl(wv, j + 4 + half), w3 = __shfl(wv, j + 6 + half);
                const float4 h0 = *(const float4*)(h + (size_t)s0 * F + q);
                const float4 h1 = *(const float4*)(h + (size_t)s1 * F + q);
                const float4 h2 = *(const float4*)(h + (size_t)s2 * F + q);
                const float4 h3 = *(const float4*)(h + (size_t)s3 * F + q);
                fma4(accA, w0, h0); fma4(accB, w1, h1);
                fma4(accC, w2, h2); fma4(accD, w3, h3);
            }
            for (; j + 4 <= cnt; j += 4) {
                const int   s0 = __shfl(sv, j + half),  s1 = __shfl(sv, j + 2 + half);
                const float w0 = __shfl(wv, j + half);
                const float w1 = __shfl(wv, j + 2 + half);
                const float4 h0 = *(const float4*)(h + (size_t)s0 * F + q);
                const float4 h1 = *(const float4*)(h + (size_t)s1 * F + q);
                fma4(accA, w0, h0); fma4(accB, w1, h1);
            }
            for (; j < cnt; j += 2) {
                const int jj = j + half;
                const int   s0 = __shfl(sv, jj);
                const float w0 = __shfl(wv, jj);
                const float4 h0 = *(const float4*)(h + (size_t)s0 * F + q);
                fma4(accA, w0, h0);
            }
        }
        float4 acc = make_float4(accA.x + accB.x + accC.x + accD.x,
                                 accA.y + accB.y + accC.y + accD.y,
                                 accA.z + accB.z + accC.z + accD.z,
                                 accA.w + accB.w + accC.w + accD.w);
        acc.x += __shfl_xor(acc.x, 32); acc.y += __shfl_xor(acc.y, 32);
        acc.z += __shfl_xor(acc.z, 32); acc.w += __shfl_xor(acc.w, 32);
        const float4 b4 = *(const float4*)(bias + q);
        float v0 = fmaf(acc.x, dn, b4.x), v1 = fmaf(acc.y, dn, b4.y);
        float v2 = fmaf(acc.z, dn, b4.z), v3 = fmaf(acc.w, dn, b4.w);
        v0 = v0 > 0.f ? v0 : 0.f; v1 = v1 > 0.f ? v1 : 0.f;
        v2 = v2 > 0.f ? v2 : 0.f; v3 = v3 > 0.f ? v3 : 0.f;
        const float4 wfa = *(const float4*)(Wf + q * 2);       // W[q][0..1], W[q+1][0..1]
        const float4 wfb = *(const float4*)(Wf + q * 2 + 4);   // W[q+2][0..1], W[q+3][0..1]
        p0 = v0 * wfa.x + v1 * wfa.z + v2 * wfb.x + v3 * wfb.z;
        p1 = v0 * wfa.y + v1 * wfa.w + v2 * wfb.y + v3 * wfb.w;
        for (int o = 16; o; o >>= 1) { p0 += __shfl_xor(p0, o); p1 += __shfl_xor(p1, o); }
    }
    if (lane == 0 && n < NN) { sg[wave] = batch[n]; sp0[wave] = p0; sp1[wave] = p1; }
    __syncthreads();
    if (threadIdx.x == 0) {
#pragma unroll
        for (int w = 0; w < 4; ++w) {
            const int g = sg[w];
            if (g < 0) continue;
            float q0 = sp0[w], q1 = sp1[w];
            for (int u = w + 1; u < 4; ++u) {
                if (sg[u] == g) { q0 += sp0[u]; q1 += sp1[u]; sg[u] = -1; }
            }
            atomicAdd(gscr + g * 32,     q0);
            atomicAdd(gscr + g * 32 + 1, q1);
        }
    }
}

// out[g,c] = gscr[g*32+c] / cnt_g + bf[c]; cnt via binary search on sorted batch
__global__ void finalize(const float* __restrict__ gscr, const int* __restrict__ batch,
                         const float* __restrict__ bf, float* __restrict__ out) {
    const int g = threadIdx.x;   // 128
    int lo = 0, hi = NN;
    while (lo < hi) { int m = (lo + hi) >> 1; if (batch[m] < g) lo = m + 1; else hi = m; }
    int lo2 = lo, hi2 = NN;
    while (lo2 < hi2) { int m = (lo2 + hi2) >> 1; if (batch[m] < g + 1) lo2 = m + 1; else hi2 = m; }
    const float inv = 1.f / fmaxf((float)(lo2 - lo), 1.f);
    out[g * 2]     = gscr[g * 32]     * inv + bf[0];
    out[g * 2 + 1] = gscr[g * 32 + 1] * inv + bf[1];
}

extern "C" void kernel_launch(void* const* d_in, const int* in_sizes, int n_in,
                              void* d_out, int out_size, void* d_ws, size_t ws_size,
                              hipStream_t stream) {
    const float* x       = (const float*)d_in[0];
    const float* W1      = (const float*)d_in[1];
    const float* att_src = (const float*)d_in[2];
    const float* att_dst = (const float*)d_in[3];
    const float* b1      = (const float*)d_in[4];
    const float* W2      = (const float*)d_in[5];
    const float* b2      = (const float*)d_in[6];
    const float* Wf      = (const float*)d_in[7];
    const float* bf      = (const float*)d_in[8];
    const int*   ei      = (const int*)d_in[9];
    const int*   batch   = (const int*)d_in[10];
    float* out = (float*)d_out;

    float* ws        = (float*)d_ws;
    float* h1        = ws;                       // [NN*F]
    float* hg        = h1 + (size_t)NN * F;      // [NN*F]
    float* h2        = hg + (size_t)NN * F;      // [NN*F]
    float* asrc      = h2 + (size_t)NN * F;      // [NN]
    float* adst      = asrc + NN;                // [NN]
    float* dinv      = adst + NN;                // [NN]
    float* gscr      = dinv + NN;                // [NG*32] padded per-graph partials
    int*   deg       = (int*)(gscr + NG * 32);   // [NN] histogram, then scatter cursor
    int*   row_start = deg + NN;                 // [NN+1]
    int*   csr_src   = row_start + NN + 1;       // [EP]
    int*   bsum      = csr_src + EP;             // [256]
    int*   boff      = bsum + 256;               // [256]

    // CSR build (independent of feature path)
    hipMemsetAsync(deg, 0, NN * sizeof(int), stream);
    hipMemsetAsync(gscr, 0, NG * 32 * sizeof(float), stream);
    hist_deg<<<(EP + 255) / 256, 256, 0, stream>>>(ei, deg);
    scan_blk<<<NB_SCAN, 256, 0, stream>>>(deg, row_start, bsum);
    scan_top<<<1, 256, 0, stream>>>(bsum, boff);
    scan_add<<<NB_SCAN, 256, 0, stream>>>(row_start, boff);
    hipMemsetAsync(deg, 0, NN * sizeof(int), stream);
    scatter_csr<<<(EP + 255) / 256, 256, 0, stream>>>(ei, row_start, deg, csr_src);

    gemm_tiled<<<(NN + 127) / 128, 512, 0, stream>>>(x, W1, h1, NN,
                                                     att_src, att_dst, asrc, adst);
    gat_gather<<<(NN + 3) / 4, 256, 0, stream>>>(row_start, csr_src, asrc, adst, h1, b1, hg);
    gemm_tiled<<<(NN + 127) / 128, 512, 0, stream>>>(hg, W2, h2, NN,
                                                     nullptr, nullptr, nullptr, nullptr);
    make_dinv<<<(NN + 255) / 256, 256, 0, stream>>>(row_start, dinv);
    gcn_gather_pool<<<(NN + 3) / 4, 256, 0, stream>>>(row_start, csr_src, dinv, h2, b2,
                                                      batch, Wf, gscr);
    finalize<<<1, NG, 0, stream>>>(gscr, batch, bf, out);
}

// Round 9
// 343.348 us; speedup vs baseline: 2.5043x; 1.0751x over previous
//
#include <hip/hip_runtime.h>

#define NN 50000
#define NE 800000
#define EP (NE + NN)      // edges + self loops = 850000
#define NG 128
#define F 128
#define SW 140            // Ws row stride (floats), fits swizzle range [0,140)
// injective W column swizzle: c + 4*(c/32). 16 col-groups -> all banks at 2-way (free).
#define SWZ(c) ((c) + (((c) >> 5) << 2))
#define NB_SCAN ((NN + 255) / 256)   // 196

__device__ inline void fma4(float4& a, float s, const float4& b) {
    a.x = fmaf(s, b.x, a.x); a.y = fmaf(s, b.y, a.y);
    a.z = fmaf(s, b.z, a.z); a.w = fmaf(s, b.w, a.w);
}

__device__ inline unsigned int bf16rn(float x) {   // RNE round to bf16 (returns low 16)
    unsigned int u = __float_as_uint(x);
    u += 0x7fffu + ((u >> 16) & 1u);
    return u >> 16;
}
__device__ inline unsigned int pack2(float a, float b) {
    return bf16rn(a) | (bf16rn(b) << 16);
}
// 8 bf16 (uint4) -> 8 fma's into acc[0..7]
__device__ inline void bf8_fma(float* acc, float w, uint4 hv) {
    acc[0] = fmaf(w, __uint_as_float(hv.x << 16), acc[0]);
    acc[1] = fmaf(w, __uint_as_float(hv.x & 0xffff0000u), acc[1]);
    acc[2] = fmaf(w, __uint_as_float(hv.y << 16), acc[2]);
    acc[3] = fmaf(w, __uint_as_float(hv.y & 0xffff0000u), acc[3]);
    acc[4] = fmaf(w, __uint_as_float(hv.z << 16), acc[4]);
    acc[5] = fmaf(w, __uint_as_float(hv.z & 0xffff0000u), acc[5]);
    acc[6] = fmaf(w, __uint_as_float(hv.w << 16), acc[6]);
    acc[7] = fmaf(w, __uint_as_float(hv.w & 0xffff0000u), acc[7]);
}

// C[N,128] = A[N,128] @ W[128,128], fp32 math, bf16 (RNE) output rows.
// Block tile 128x128, 512 threads, thread tile 4x8.
// Optional fused epilogue: asrc[n]=C[n,:]@att_src, adst[n]=C[n,:]@att_dst (fp32 acc).
__global__ __launch_bounds__(512, 1) void gemm_tiled(const float* __restrict__ A,
                                                     const float* __restrict__ W,
                                                     unsigned short* __restrict__ Cb, int N,
                                                     const float* __restrict__ att_src,
                                                     const float* __restrict__ att_dst,
                                                     float* __restrict__ asrc,
                                                     float* __restrict__ adst) {
    __shared__ float As[128 * 128];   // [row][(k+rot)&127], rot = 8*((row>>3)&3)
    __shared__ float Ws[128 * SW];    // [k][SWZ(col)]
    const int tid = threadIdx.x;
    const int row0 = blockIdx.x * 128;
#pragma unroll
    for (int i = 0; i < 8; ++i) {
        const int idx = i * 512 + tid;          // 0..4095
        const int r = idx >> 5;                 // k-row for W, node-row for A
        const int c4 = (idx & 31) << 2;
        const float4 wv = *(const float4*)(W + r * F + c4);
        *(float4*)(Ws + r * SW + SWZ(c4)) = wv;
        const int gr = row0 + r;
        const float4 av = (gr < N) ? *(const float4*)(A + (size_t)gr * F + c4)
                                   : make_float4(0.f, 0.f, 0.f, 0.f);
        *(float4*)(As + r * 128 + ((c4 + 8 * ((r >> 3) & 3)) & 127)) = av;
    }
    __syncthreads();
    const int rg = tid >> 4, cg = tid & 15;     // rg 0..31, cg 0..15
    const int r0 = rg * 4, c0 = cg * 8;
    const int rot_a = 8 * ((rg >> 1) & 3);      // rows r0..r0+3 share (row>>3)&3
    const int co0 = SWZ(c0);
    const int co1 = SWZ(c0 + 4);
    float4 acc[4][2] = {};
    for (int k4 = 0; k4 < F; k4 += 4) {
        const int ka = (k4 + rot_a) & 127;
        float4 a[4];
#pragma unroll
        for (int r = 0; r < 4; ++r) a[r] = *(const float4*)(As + (r0 + r) * 128 + ka);
#pragma unroll
        for (int j = 0; j < 4; ++j) {
            const float4 w0 = *(const float4*)(Ws + (k4 + j) * SW + co0);
            const float4 w1 = *(const float4*)(Ws + (k4 + j) * SW + co1);
#pragma unroll
            for (int r = 0; r < 4; ++r) {
                const float aj = ((const float*)&a[r])[j];
                fma4(acc[r][0], aj, w0);
                fma4(acc[r][1], aj, w1);
            }
        }
    }
#pragma unroll
    for (int r = 0; r < 4; ++r) {
        const int gr = row0 + r0 + r;
        if (gr < N) {
            uint4 pk;
            pk.x = pack2(acc[r][0].x, acc[r][0].y);
            pk.y = pack2(acc[r][0].z, acc[r][0].w);
            pk.z = pack2(acc[r][1].x, acc[r][1].y);
            pk.w = pack2(acc[r][1].z, acc[r][1].w);
            *(uint4*)(Cb + (size_t)gr * F + c0) = pk;
        }
    }
    if (asrc) {   // fused attention-score epilogue (gemm1 only), fp32 accumulators
        const float4 sa0 = *(const float4*)(att_src + c0);
        const float4 sa1 = *(const float4*)(att_src + c0 + 4);
        const float4 da0 = *(const float4*)(att_dst + c0);
        const float4 da1 = *(const float4*)(att_dst + c0 + 4);
#pragma unroll
        for (int r = 0; r < 4; ++r) {
            float ps = acc[r][0].x * sa0.x + acc[r][0].y * sa0.y + acc[r][0].z * sa0.z +
                       acc[r][0].w * sa0.w + acc[r][1].x * sa1.x + acc[r][1].y * sa1.y +
                       acc[r][1].z * sa1.z + acc[r][1].w * sa1.w;
            float pd = acc[r][0].x * da0.x + acc[r][0].y * da0.y + acc[r][0].z * da0.z +
                       acc[r][0].w * da0.w + acc[r][1].x * da1.x + acc[r][1].y * da1.y +
                       acc[r][1].z * da1.z + acc[r][1].w * da1.w;
#pragma unroll
            for (int o = 8; o; o >>= 1) { ps += __shfl_xor(ps, o); pd += __shfl_xor(pd, o); }
            if (cg == 0) {
                const int gr = row0 + r0 + r;
                if (gr < N) { asrc[gr] = ps; adst[gr] = pd; }
            }
        }
    }
}

// ---- CSR build: histogram -> hierarchical scan -> scatter ----
__global__ void hist_deg(const int* __restrict__ ei, int* __restrict__ deg) {
    const int e = blockIdx.x * blockDim.x + threadIdx.x;
    if (e >= EP) return;
    const int d = (e < NE) ? ei[NE + e] : e - NE;
    atomicAdd(deg + d, 1);
}

__global__ void scan_blk(const int* __restrict__ deg, int* __restrict__ rs,
                         int* __restrict__ bsum) {
    __shared__ int sh[256];
    const int t = threadIdx.x;
    const int i = blockIdx.x * 256 + t;
    const int v = (i < NN) ? deg[i] : 0;
    sh[t] = v;
    __syncthreads();
    for (int o = 1; o < 256; o <<= 1) {
        const int u = (t >= o) ? sh[t - o] : 0;
        __syncthreads();
        sh[t] += u;
        __syncthreads();
    }
    if (i < NN) rs[i] = sh[t] - v;
    if (t == 255) bsum[blockIdx.x] = sh[255];
}

__global__ void scan_top(const int* __restrict__ bsum, int* __restrict__ boff) {
    __shared__ int sh[256];
    const int t = threadIdx.x;
    const int v = (t < NB_SCAN) ? bsum[t] : 0;
    sh[t] = v;
    __syncthreads();
    for (int o = 1; o < 256; o <<= 1) {
        const int u = (t >= o) ? sh[t - o] : 0;
        __syncthreads();
        sh[t] += u;
        __syncthreads();
    }
    if (t < NB_SCAN) boff[t] = sh[t] - v;
}

__global__ void scan_add(int* __restrict__ rs, const int* __restrict__ boff) {
    const int i = blockIdx.x * 256 + threadIdx.x;
    if (i < NN) rs[i] += boff[blockIdx.x];
    if (i == 0) rs[NN] = EP;   // total is statically known
}

__global__ void scatter_csr(const int* __restrict__ ei, const int* __restrict__ row_start,
                            int* __restrict__ cnt, int* __restrict__ csr_src) {
    const int e = blockIdx.x * blockDim.x + threadIdx.x;
    if (e >= EP) return;
    int s, d;
    if (e < NE) { s = ei[e]; d = ei[NE + e]; } else { s = d = e - NE; }
    const int pos = row_start[d] + atomicAdd(cnt + d, 1);
    csr_src[pos] = s;
}

// ---- GAT gather: one wave per dst node over bf16 rows (256 B).
// 16 lanes per row (uint4 = 8 bf16 each) -> 4 edges per wave-instruction;
// indices+exp-weights prefetched 64-wide, broadcast 2 shfls / 4 edges.
__global__ void gat_gather(const int* __restrict__ row_start, const int* __restrict__ csr_src,
                           const float* __restrict__ asrc, const float* __restrict__ adst,
                           const unsigned short* __restrict__ hb, const float* __restrict__ bias,
                           float* __restrict__ out) {
    const int n = blockIdx.x * 4 + (threadIdx.x >> 6);
    const int lane = threadIdx.x & 63;
    if (n >= NN) return;
    const int quarter = lane >> 4;
    const int qo = (lane & 15) << 3;    // 8-feature group within the row
    const int lo = row_start[n], hi = row_start[n + 1];
    const float adn = adst[n];
    float den = 0.f;
    float accA[8] = {}, accB[8] = {};
    for (int base = lo; base < hi; base += 64) {
        const int cnt = min(64, hi - base);
        const int sv = (lane < cnt) ? csr_src[base + lane] : 0;
        float ev = 0.f;
        if (lane < cnt) {
            float sc = asrc[sv] + adn;
            sc = sc > 0.f ? sc : 0.2f * sc;
            ev = __expf(sc);
        }
        den += ev;                      // lanes >= cnt contribute 0
        int j = 0;
        for (; j + 16 <= cnt; j += 16) {
#pragma unroll
            for (int t = 0; t < 4; ++t) {
                const int jj = j + 4 * t + quarter;
                const int   s = __shfl(sv, jj);
                const float w = __shfl(ev, jj);
                const uint4 hv = *(const uint4*)(hb + (size_t)s * F + qo);
                bf8_fma((t & 1) ? accB : accA, w, hv);
            }
        }
        for (; j < cnt; j += 4) {       // j multiple of 4 -> jj <= 63; ev=0 pads
            const int jj = j + quarter;
            const int   s = __shfl(sv, jj);
            const float w = __shfl(ev, jj);
            const uint4 hv = *(const uint4*)(hb + (size_t)s * F + qo);
            bf8_fma(accA, w, hv);
        }
    }
    float acc[8];
#pragma unroll
    for (int i = 0; i < 8; ++i) {
        float v = accA[i] + accB[i];
        v += __shfl_xor(v, 16);
        v += __shfl_xor(v, 32);
        acc[i] = v;
    }
    for (int o = 32; o; o >>= 1) den += __shfl_xor(den, o);
    const float inv = 1.f / den;        // den > 0 (self loop)
    if (lane < 16) {
        const float4 b0 = *(const float4*)(bias + qo);
        const float4 b1 = *(const float4*)(bias + qo + 4);
        float4 v0, v1;
        v0.x = fmaf(acc[0], inv, b0.x); v0.y = fmaf(acc[1], inv, b0.y);
        v0.z = fmaf(acc[2], inv, b0.z); v0.w = fmaf(acc[3], inv, b0.w);
        v1.x = fmaf(acc[4], inv, b1.x); v1.y = fmaf(acc[5], inv, b1.y);
        v1.z = fmaf(acc[6], inv, b1.z); v1.w = fmaf(acc[7], inv, b1.w);
        v0.x = v0.x > 0.f ? v0.x : 0.f; v0.y = v0.y > 0.f ? v0.y : 0.f;
        v0.z = v0.z > 0.f ? v0.z : 0.f; v0.w = v0.w > 0.f ? v0.w : 0.f;
        v1.x = v1.x > 0.f ? v1.x : 0.f; v1.y = v1.y > 0.f ? v1.y : 0.f;
        v1.z = v1.z > 0.f ? v1.z : 0.f; v1.w = v1.w > 0.f ? v1.w : 0.f;
        *(float4*)(out + (size_t)n * F + qo) = v0;
        *(float4*)(out + (size_t)n * F + qo + 4) = v1;
    }
}

__global__ void make_dinv(const int* __restrict__ row_start, float* __restrict__ dinv) {
    const int n = blockIdx.x * blockDim.x + threadIdx.x;
    if (n >= NN) return;
    dinv[n] = rsqrtf((float)(row_start[n + 1] - row_start[n]));
}

// ---- GCN gather over bf16 rows + fused mean-pool/head partials.
__global__ void gcn_gather_pool(const int* __restrict__ row_start, const int* __restrict__ csr_src,
                                const float* __restrict__ dinv, const unsigned short* __restrict__ hb,
                                const float* __restrict__ bias, const int* __restrict__ batch,
                                const float* __restrict__ Wf, float* __restrict__ gscr) {
    __shared__ int   sg[4];
    __shared__ float sp0[4], sp1[4];
    const int wave = threadIdx.x >> 6;
    const int n = blockIdx.x * 4 + wave;
    const int lane = threadIdx.x & 63;
    const int quarter = lane >> 4;
    const int qo = (lane & 15) << 3;
    if (threadIdx.x < 4) sg[threadIdx.x] = -1;
    float p0 = 0.f, p1 = 0.f;
    if (n < NN) {
        const int lo = row_start[n], hi = row_start[n + 1];
        const float dn = dinv[n];
        float accA[8] = {}, accB[8] = {};
        for (int base = lo; base < hi; base += 64) {
            const int cnt = min(64, hi - base);
            const int sv = (lane < cnt) ? csr_src[base + lane] : 0;
            const float wv = (lane < cnt) ? dinv[sv] : 0.f;
            int j = 0;
            for (; j + 16 <= cnt; j += 16) {
#pragma unroll
                for (int t = 0; t < 4; ++t) {
                    const int jj = j + 4 * t + quarter;
                    const int   s = __shfl(sv, jj);
                    const float w = __shfl(wv, jj);
                    const uint4 hv = *(const uint4*)(hb + (size_t)s * F + qo);
                    bf8_fma((t & 1) ? accB : accA, w, hv);
                }
            }
            for (; j < cnt; j += 4) {
                const int jj = j + quarter;
                const int   s = __shfl(sv, jj);
                const float w = __shfl(wv, jj);
                const uint4 hv = *(const uint4*)(hb + (size_t)s * F + qo);
                bf8_fma(accA, w, hv);
            }
        }
        float v[8];
#pragma unroll
        for (int i = 0; i < 8; ++i) {
            float a = accA[i] + accB[i];
            a += __shfl_xor(a, 16);
            a += __shfl_xor(a, 32);
            v[i] = fmaf(a, dn, bias[qo + i]);
            v[i] = v[i] > 0.f ? v[i] : 0.f;
        }
        // project to 2 classes: Wf rows qo..qo+7, layout [row][2] interleaved
        const float4 w0 = *(const float4*)(Wf + qo * 2);        // rows qo, qo+1
        const float4 w1 = *(const float4*)(Wf + qo * 2 + 4);    // rows qo+2, qo+3
        const float4 w2 = *(const float4*)(Wf + qo * 2 + 8);    // rows qo+4, qo+5
        const float4 w3 = *(const float4*)(Wf + qo * 2 + 12);   // rows qo+6, qo+7
        p0 = v[0]*w0.x + v[1]*w0.z + v[2]*w1.x + v[3]*w1.z +
             v[4]*w2.x + v[5]*w2.z + v[6]*w3.x + v[7]*w3.z;
        p1 = v[0]*w0.y + v[1]*w0.w + v[2]*w1.y + v[3]*w1.w +
             v[4]*w2.y + v[5]*w2.w + v[6]*w3.y + v[7]*w3.w;
        // reduce within the 16-lane group only (quarters hold identical copies)
        for (int o = 8; o; o >>= 1) { p0 += __shfl_xor(p0, o); p1 += __shfl_xor(p1, o); }
    }
    if (lane == 0 && n < NN) { sg[wave] = batch[n]; sp0[wave] = p0; sp1[wave] = p1; }
    __syncthreads();
    if (threadIdx.x == 0) {
#pragma unroll
        for (int w = 0; w < 4; ++w) {
            const int g = sg[w];
            if (g < 0) continue;
            float q0 = sp0[w], q1 = sp1[w];
            for (int u = w + 1; u < 4; ++u) {
                if (sg[u] == g) { q0 += sp0[u]; q1 += sp1[u]; sg[u] = -1; }
            }
            atomicAdd(gscr + g * 32,     q0);
            atomicAdd(gscr + g * 32 + 1, q1);
        }
    }
}

// out[g,c] = gscr[g*32+c] / cnt_g + bf[c]; cnt via binary search on sorted batch
__global__ void finalize(const float* __restrict__ gscr, const int* __restrict__ batch,
                         const float* __restrict__ bf, float* __restrict__ out) {
    const int g = threadIdx.x;   // 128
    int lo = 0, hi = NN;
    while (lo < hi) { int m = (lo + hi) >> 1; if (batch[m] < g) lo = m + 1; else hi = m; }
    int lo2 = lo, hi2 = NN;
    while (lo2 < hi2) { int m = (lo2 + hi2) >> 1; if (batch[m] < g + 1) lo2 = m + 1; else hi2 = m; }
    const float inv = 1.f / fmaxf((float)(lo2 - lo), 1.f);
    out[g * 2]     = gscr[g * 32]     * inv + bf[0];
    out[g * 2 + 1] = gscr[g * 32 + 1] * inv + bf[1];
}

extern "C" void kernel_launch(void* const* d_in, const int* in_sizes, int n_in,
                              void* d_out, int out_size, void* d_ws, size_t ws_size,
                              hipStream_t stream) {
    const float* x       = (const float*)d_in[0];
    const float* W1      = (const float*)d_in[1];
    const float* att_src = (const float*)d_in[2];
    const float* att_dst = (const float*)d_in[3];
    const float* b1      = (const float*)d_in[4];
    const float* W2      = (const float*)d_in[5];
    const float* b2      = (const float*)d_in[6];
    const float* Wf      = (const float*)d_in[7];
    const float* bf      = (const float*)d_in[8];
    const int*   ei      = (const int*)d_in[9];
    const int*   batch   = (const int*)d_in[10];
    float* out = (float*)d_out;

    float* ws             = (float*)d_ws;
    float* hg             = ws;                                   // [NN*F] fp32 GAT out
    unsigned short* h1b   = (unsigned short*)(hg + (size_t)NN * F); // [NN*F] bf16 gemm1 out
    unsigned short* h2b   = h1b + (size_t)NN * F;                 // [NN*F] bf16 gemm2 out
    float* asrc      = (float*)(h2b + (size_t)NN * F);            // [NN]
    float* adst      = asrc + NN;                                 // [NN]
    float* dinv      = adst + NN;                                 // [NN]
    float* gscr      = dinv + NN;                                 // [NG*32]
    int*   deg       = (int*)(gscr + NG * 32);                    // [NN]
    int*   row_start = deg + NN;                                  // [NN+1]
    int*   csr_src   = row_start + NN + 1;                        // [EP]
    int*   bsum      = csr_src + EP;                              // [256]
    int*   boff      = bsum + 256;                                // [256]

    // CSR build (independent of feature path)
    hipMemsetAsync(deg, 0, NN * sizeof(int), stream);
    hipMemsetAsync(gscr, 0, NG * 32 * sizeof(float), stream);
    hist_deg<<<(EP + 255) / 256, 256, 0, stream>>>(ei, deg);
    scan_blk<<<NB_SCAN, 256, 0, stream>>>(deg, row_start, bsum);
    scan_top<<<1, 256, 0, stream>>>(bsum, boff);
    scan_add<<<NB_SCAN, 256, 0, stream>>>(row_start, boff);
    hipMemsetAsync(deg, 0, NN * sizeof(int), stream);
    scatter_csr<<<(EP + 255) / 256, 256, 0, stream>>>(ei, row_start, deg, csr_src);

    gemm_tiled<<<(NN + 127) / 128, 512, 0, stream>>>(x, W1, h1b, NN,
                                                     att_src, att_dst, asrc, adst);
    gat_gather<<<(NN + 3) / 4, 256, 0, stream>>>(row_start, csr_src, asrc, adst, h1b, b1, hg);
    gemm_tiled<<<(NN + 127) / 128, 512, 0, stream>>>(hg, W2, h2b, NN,
                                                     nullptr, nullptr, nullptr, nullptr);
    make_dinv<<<(NN + 255) / 256, 256, 0, stream>>>(row_start, dinv);
    gcn_gather_pool<<<(NN + 3) / 4, 256, 0, stream>>>(row_start, csr_src, dinv, h2b, b2,
                                                      batch, Wf, gscr);
    finalize<<<1, NG, 0, stream>>>(gscr, batch, bf, out);
}

// Round 10
// 321.745 us; speedup vs baseline: 2.6725x; 1.0671x over previous
//
#include <hip/hip_runtime.h>

#define NN 50000
#define NE 800000
#define EP (NE + NN)      // edges + self loops = 850000
#define NG 128
#define F 128
#define SW 140            // Ws row stride (floats), fits swizzle range [0,140)
// injective W column swizzle: c + 4*(c/32). 16 col-groups -> all banks at 2-way (free).
#define SWZ(c) ((c) + (((c) >> 5) << 2))
#define NBE 208           // edge-pass blocks
#define EPB 4096          // edges per block (208*4096 >= EP)
#define NBUCK 196         // dst buckets of 256 nodes
#define CMAT (NBUCK * NBE)
#define BCAP 6144         // per-bucket edge cap (mean 4352, sigma ~64 -> 28 sigma)

__device__ inline void fma4(float4& a, float s, const float4& b) {
    a.x = fmaf(s, b.x, a.x); a.y = fmaf(s, b.y, a.y);
    a.z = fmaf(s, b.z, a.z); a.w = fmaf(s, b.w, a.w);
}

__device__ inline unsigned int bf16rn(float x) {   // RNE round to bf16 (returns low 16)
    unsigned int u = __float_as_uint(x);
    u += 0x7fffu + ((u >> 16) & 1u);
    return u >> 16;
}
__device__ inline unsigned int pack2(float a, float b) {
    return bf16rn(a) | (bf16rn(b) << 16);
}
// 8 bf16 (uint4) -> 8 fma's into acc[0..7]
__device__ inline void bf8_fma(float* acc, float w, uint4 hv) {
    acc[0] = fmaf(w, __uint_as_float(hv.x << 16), acc[0]);
    acc[1] = fmaf(w, __uint_as_float(hv.x & 0xffff0000u), acc[1]);
    acc[2] = fmaf(w, __uint_as_float(hv.y << 16), acc[2]);
    acc[3] = fmaf(w, __uint_as_float(hv.y & 0xffff0000u), acc[3]);
    acc[4] = fmaf(w, __uint_as_float(hv.z << 16), acc[4]);
    acc[5] = fmaf(w, __uint_as_float(hv.z & 0xffff0000u), acc[5]);
    acc[6] = fmaf(w, __uint_as_float(hv.w << 16), acc[6]);
    acc[7] = fmaf(w, __uint_as_float(hv.w & 0xffff0000u), acc[7]);
}

// C[N,128] = A[N,128] @ W[128,128], fp32 math, bf16 (RNE) output rows.
__global__ __launch_bounds__(512, 1) void gemm_tiled(const float* __restrict__ A,
                                                     const float* __restrict__ W,
                                                     unsigned short* __restrict__ Cb, int N,
                                                     const float* __restrict__ att_src,
                                                     const float* __restrict__ att_dst,
                                                     float* __restrict__ asrc,
                                                     float* __restrict__ adst) {
    __shared__ float As[128 * 128];   // [row][(k+rot)&127], rot = 8*((row>>3)&3)
    __shared__ float Ws[128 * SW];    // [k][SWZ(col)]
    const int tid = threadIdx.x;
    const int row0 = blockIdx.x * 128;
#pragma unroll
    for (int i = 0; i < 8; ++i) {
        const int idx = i * 512 + tid;          // 0..4095
        const int r = idx >> 5;                 // k-row for W, node-row for A
        const int c4 = (idx & 31) << 2;
        const float4 wv = *(const float4*)(W + r * F + c4);
        *(float4*)(Ws + r * SW + SWZ(c4)) = wv;
        const int gr = row0 + r;
        const float4 av = (gr < N) ? *(const float4*)(A + (size_t)gr * F + c4)
                                   : make_float4(0.f, 0.f, 0.f, 0.f);
        *(float4*)(As + r * 128 + ((c4 + 8 * ((r >> 3) & 3)) & 127)) = av;
    }
    __syncthreads();
    const int rg = tid >> 4, cg = tid & 15;     // rg 0..31, cg 0..15
    const int r0 = rg * 4, c0 = cg * 8;
    const int rot_a = 8 * ((rg >> 1) & 3);      // rows r0..r0+3 share (row>>3)&3
    const int co0 = SWZ(c0);
    const int co1 = SWZ(c0 + 4);
    float4 acc[4][2] = {};
    for (int k4 = 0; k4 < F; k4 += 4) {
        const int ka = (k4 + rot_a) & 127;
        float4 a[4];
#pragma unroll
        for (int r = 0; r < 4; ++r) a[r] = *(const float4*)(As + (r0 + r) * 128 + ka);
#pragma unroll
        for (int j = 0; j < 4; ++j) {
            const float4 w0 = *(const float4*)(Ws + (k4 + j) * SW + co0);
            const float4 w1 = *(const float4*)(Ws + (k4 + j) * SW + co1);
#pragma unroll
            for (int r = 0; r < 4; ++r) {
                const float aj = ((const float*)&a[r])[j];
                fma4(acc[r][0], aj, w0);
                fma4(acc[r][1], aj, w1);
            }
        }
    }
#pragma unroll
    for (int r = 0; r < 4; ++r) {
        const int gr = row0 + r0 + r;
        if (gr < N) {
            uint4 pk;
            pk.x = pack2(acc[r][0].x, acc[r][0].y);
            pk.y = pack2(acc[r][0].z, acc[r][0].w);
            pk.z = pack2(acc[r][1].x, acc[r][1].y);
            pk.w = pack2(acc[r][1].z, acc[r][1].w);
            *(uint4*)(Cb + (size_t)gr * F + c0) = pk;
        }
    }
    if (asrc) {   // fused attention-score epilogue (gemm1 only), fp32 accumulators
        const float4 sa0 = *(const float4*)(att_src + c0);
        const float4 sa1 = *(const float4*)(att_src + c0 + 4);
        const float4 da0 = *(const float4*)(att_dst + c0);
        const float4 da1 = *(const float4*)(att_dst + c0 + 4);
#pragma unroll
        for (int r = 0; r < 4; ++r) {
            float ps = acc[r][0].x * sa0.x + acc[r][0].y * sa0.y + acc[r][0].z * sa0.z +
                       acc[r][0].w * sa0.w + acc[r][1].x * sa1.x + acc[r][1].y * sa1.y +
                       acc[r][1].z * sa1.z + acc[r][1].w * sa1.w;
            float pd = acc[r][0].x * da0.x + acc[r][0].y * da0.y + acc[r][0].z * da0.z +
                       acc[r][0].w * da0.w + acc[r][1].x * da1.x + acc[r][1].y * da1.y +
                       acc[r][1].z * da1.z + acc[r][1].w * da1.w;
#pragma unroll
            for (int o = 8; o; o >>= 1) { ps += __shfl_xor(ps, o); pd += __shfl_xor(pd, o); }
            if (cg == 0) {
                const int gr = row0 + r0 + r;
                if (gr < N) { asrc[gr] = ps; adst[gr] = pd; }
            }
        }
    }
}

// ---- CSR build via bucketed counting sort (bucket = dst>>8) ----
__global__ void bin_count(const int* __restrict__ ei, int* __restrict__ cmat) {
    __shared__ int lcnt[NBUCK];
    const int t = threadIdx.x, b = blockIdx.x;
    for (int i = t; i < NBUCK; i += 256) lcnt[i] = 0;
    __syncthreads();
    const int e0 = b * EPB;
#pragma unroll
    for (int i = 0; i < EPB / 256; ++i) {
        const int e = e0 + i * 256 + t;
        if (e < EP) {
            const int d = (e < NE) ? ei[NE + e] : e - NE;
            atomicAdd(&lcnt[d >> 8], 1);
        }
    }
    __syncthreads();
    for (int i = t; i < NBUCK; i += 256) cmat[i * NBE + b] = lcnt[i];
}

// in-place exclusive scan of cmat[CMAT] (bucket-major), one block of 1024
__global__ void scan_all(int* __restrict__ cmat) {
    __shared__ int part[1024];
    const int t = threadIdx.x;
    const int CH = (CMAT + 1023) / 1024;   // 40
    int loc[(CMAT + 1023) / 1024];
    const int lo = t * CH;
    int s = 0;
#pragma unroll
    for (int i = 0; i < CH; ++i) {
        const int j = lo + i;
        const int v = (j < CMAT) ? cmat[j] : 0;
        loc[i] = s; s += v;
    }
    part[t] = s;
    __syncthreads();
    for (int o = 1; o < 1024; o <<= 1) {
        const int u = (t >= o) ? part[t - o] : 0;
        __syncthreads();
        part[t] += u;
        __syncthreads();
    }
    const int base = part[t] - s;
#pragma unroll
    for (int i = 0; i < CH; ++i) {
        const int j = lo + i;
        if (j < CMAT) cmat[j] = base + loc[i];
    }
}

// deterministic bucket scatter: pack src(16b)|dloc(8b)<<16 into u32
__global__ void bin_scatter(const int* __restrict__ ei, const int* __restrict__ cmat,
                            unsigned int* __restrict__ ebuf) {
    __shared__ int cur[NBUCK];
    const int t = threadIdx.x, b = blockIdx.x;
    for (int i = t; i < NBUCK; i += 256) cur[i] = cmat[i * NBE + b];
    __syncthreads();
    const int e0 = b * EPB;
#pragma unroll
    for (int i = 0; i < EPB / 256; ++i) {
        const int e = e0 + i * 256 + t;
        if (e < EP) {
            int s, d;
            if (e < NE) { s = ei[e]; d = ei[NE + e]; } else { s = d = e - NE; }
            const int p = atomicAdd(&cur[d >> 8], 1);
            ebuf[p] = (unsigned int)s | ((unsigned int)(d & 255) << 16);
        }
    }
}

// per-bucket LDS counting sort by exact dst -> row_start + ushort csr
__global__ void bucket_sort(const unsigned int* __restrict__ ebuf, const int* __restrict__ cmat,
                            int* __restrict__ row_start, unsigned short* __restrict__ csr16) {
    __shared__ unsigned int earr[BCAP];
    __shared__ unsigned short out16[BCAP];
    __shared__ int ecnt[256], epre[256];
    const int t = threadIdx.x, g = blockIdx.x;
    const int bstart = cmat[g * NBE];
    const int bend = (g == NBUCK - 1) ? EP : cmat[(g + 1) * NBE];
    const int m = bend - bstart;
    ecnt[t] = 0;
    __syncthreads();
    for (int i = t; i < m; i += 256) {
        const unsigned int v = ebuf[bstart + i];
        earr[i] = v;
        atomicAdd(&ecnt[v >> 16], 1);
    }
    __syncthreads();
    const int v0 = ecnt[t];
    epre[t] = v0;
    __syncthreads();
    for (int o = 1; o < 256; o <<= 1) {
        const int u = (t >= o) ? epre[t - o] : 0;
        __syncthreads();
        epre[t] += u;
        __syncthreads();
    }
    const int my_excl = epre[t] - v0;
    const int n = g * 256 + t;
    if (n <= NN) row_start[n] = bstart + my_excl;   // n==NN lands in g=195,t=80 -> EP
    ecnt[t] = my_excl;                              // reuse as cursor
    __syncthreads();
    for (int i = t; i < m; i += 256) {
        const unsigned int v = earr[i];
        const int p = atomicAdd(&ecnt[v >> 16], 1);
        out16[p] = (unsigned short)(v & 0xffffu);
    }
    __syncthreads();
    for (int i = t; i < m; i += 256) csr16[bstart + i] = out16[i];
}

// ---- GAT gather: one wave per dst node over bf16 rows (256 B).
__global__ void gat_gather(const int* __restrict__ row_start, const unsigned short* __restrict__ csr_src,
                           const float* __restrict__ asrc, const float* __restrict__ adst,
                           const unsigned short* __restrict__ hb, const float* __restrict__ bias,
                           float* __restrict__ out) {
    const int n = blockIdx.x * 4 + (threadIdx.x >> 6);
    const int lane = threadIdx.x & 63;
    if (n >= NN) return;
    const int quarter = lane >> 4;
    const int qo = (lane & 15) << 3;    // 8-feature group within the row
    const int lo = row_start[n], hi = row_start[n + 1];
    const float adn = adst[n];
    float den = 0.f;
    float accA[8] = {}, accB[8] = {};
    for (int base = lo; base < hi; base += 64) {
        const int cnt = min(64, hi - base);
        const int sv = (lane < cnt) ? (int)csr_src[base + lane] : 0;
        float ev = 0.f;
        if (lane < cnt) {
            float sc = asrc[sv] + adn;
            sc = sc > 0.f ? sc : 0.2f * sc;
            ev = __expf(sc);
        }
        den += ev;                      // lanes >= cnt contribute 0
        int j = 0;
        for (; j + 16 <= cnt; j += 16) {
#pragma unroll
            for (int t = 0; t < 4; ++t) {
                const int jj = j + 4 * t + quarter;
                const int   s = __shfl(sv, jj);
                const float w = __shfl(ev, jj);
                const uint4 hv = *(const uint4*)(hb + (size_t)s * F + qo);
                bf8_fma((t & 1) ? accB : accA, w, hv);
            }
        }
        for (; j < cnt; j += 4) {       // j multiple of 4 -> jj <= 63; ev=0 pads
            const int jj = j + quarter;
            const int   s = __shfl(sv, jj);
            const float w = __shfl(ev, jj);
            const uint4 hv = *(const uint4*)(hb + (size_t)s * F + qo);
            bf8_fma(accA, w, hv);
        }
    }
    float acc[8];
#pragma unroll
    for (int i = 0; i < 8; ++i) {
        float v = accA[i] + accB[i];
        v += __shfl_xor(v, 16);
        v += __shfl_xor(v, 32);
        acc[i] = v;
    }
    for (int o = 32; o; o >>= 1) den += __shfl_xor(den, o);
    const float inv = 1.f / den;        // den > 0 (self loop)
    if (lane < 16) {
        const float4 b0 = *(const float4*)(bias + qo);
        const float4 b1 = *(const float4*)(bias + qo + 4);
        float4 v0, v1;
        v0.x = fmaf(acc[0], inv, b0.x); v0.y = fmaf(acc[1], inv, b0.y);
        v0.z = fmaf(acc[2], inv, b0.z); v0.w = fmaf(acc[3], inv, b0.w);
        v1.x = fmaf(acc[4], inv, b1.x); v1.y = fmaf(acc[5], inv, b1.y);
        v1.z = fmaf(acc[6], inv, b1.z); v1.w = fmaf(acc[7], inv, b1.w);
        v0.x = v0.x > 0.f ? v0.x : 0.f; v0.y = v0.y > 0.f ? v0.y : 0.f;
        v0.z = v0.z > 0.f ? v0.z : 0.f; v0.w = v0.w > 0.f ? v0.w : 0.f;
        v1.x = v1.x > 0.f ? v1.x : 0.f; v1.y = v1.y > 0.f ? v1.y : 0.f;
        v1.z = v1.z > 0.f ? v1.z : 0.f; v1.w = v1.w > 0.f ? v1.w : 0.f;
        *(float4*)(out + (size_t)n * F + qo) = v0;
        *(float4*)(out + (size_t)n * F + qo + 4) = v1;
    }
}

__global__ void make_dinv(const int* __restrict__ row_start, float* __restrict__ dinv) {
    const int n = blockIdx.x * blockDim.x + threadIdx.x;
    if (n >= NN) return;
    dinv[n] = rsqrtf((float)(row_start[n + 1] - row_start[n]));
}

// ---- GCN gather over bf16 rows + fused mean-pool/head partials.
__global__ void gcn_gather_pool(const int* __restrict__ row_start, const unsigned short* __restrict__ csr_src,
                                const float* __restrict__ dinv, const unsigned short* __restrict__ hb,
                                const float* __restrict__ bias, const int* __restrict__ batch,
                                const float* __restrict__ Wf, float* __restrict__ gscr) {
    __shared__ int   sg[4];
    __shared__ float sp0[4], sp1[4];
    const int wave = threadIdx.x >> 6;
    const int n = blockIdx.x * 4 + wave;
    const int lane = threadIdx.x & 63;
    const int quarter = lane >> 4;
    const int qo = (lane & 15) << 3;
    if (threadIdx.x < 4) sg[threadIdx.x] = -1;
    float p0 = 0.f, p1 = 0.f;
    if (n < NN) {
        const int lo = row_start[n], hi = row_start[n + 1];
        const float dn = dinv[n];
        float accA[8] = {}, accB[8] = {};
        for (int base = lo; base < hi; base += 64) {
            const int cnt = min(64, hi - base);
            const int sv = (lane < cnt) ? (int)csr_src[base + lane] : 0;
            const float wv = (lane < cnt) ? dinv[sv] : 0.f;
            int j = 0;
            for (; j + 16 <= cnt; j += 16) {
#pragma unroll
                for (int t = 0; t < 4; ++t) {
                    const int jj = j + 4 * t + quarter;
                    const int   s = __shfl(sv, jj);
                    const float w = __shfl(wv, jj);
                    const uint4 hv = *(const uint4*)(hb + (size_t)s * F + qo);
                    bf8_fma((t & 1) ? accB : accA, w, hv);
                }
            }
            for (; j < cnt; j += 4) {
                const int jj = j + quarter;
                const int   s = __shfl(sv, jj);
                const float w = __shfl(wv, jj);
                const uint4 hv = *(const uint4*)(hb + (size_t)s * F + qo);
                bf8_fma(accA, w, hv);
            }
        }
        float v[8];
#pragma unroll
        for (int i = 0; i < 8; ++i) {
            float a = accA[i] + accB[i];
            a += __shfl_xor(a, 16);
            a += __shfl_xor(a, 32);
            v[i] = fmaf(a, dn, bias[qo + i]);
            v[i] = v[i] > 0.f ? v[i] : 0.f;
        }
        const float4 w0 = *(const float4*)(Wf + qo * 2);
        const float4 w1 = *(const float4*)(Wf + qo * 2 + 4);
        const float4 w2 = *(const float4*)(Wf + qo * 2 + 8);
        const float4 w3 = *(const float4*)(Wf + qo * 2 + 12);
        p0 = v[0]*w0.x + v[1]*w0.z + v[2]*w1.x + v[3]*w1.z +
             v[4]*w2.x + v[5]*w2.z + v[6]*w3.x + v[7]*w3.z;
        p1 = v[0]*w0.y + v[1]*w0.w + v[2]*w1.y + v[3]*w1.w +
             v[4]*w2.y + v[5]*w2.w + v[6]*w3.y + v[7]*w3.w;
        for (int o = 8; o; o >>= 1) { p0 += __shfl_xor(p0, o); p1 += __shfl_xor(p1, o); }
    }
    if (lane == 0 && n < NN) { sg[wave] = batch[n]; sp0[wave] = p0; sp1[wave] = p1; }
    __syncthreads();
    if (threadIdx.x == 0) {
#pragma unroll
        for (int w = 0; w < 4; ++w) {
            const int g = sg[w];
            if (g < 0) continue;
            float q0 = sp0[w], q1 = sp1[w];
            for (int u = w + 1; u < 4; ++u) {
                if (sg[u] == g) { q0 += sp0[u]; q1 += sp1[u]; sg[u] = -1; }
            }
            atomicAdd(gscr + g * 32,     q0);
            atomicAdd(gscr + g * 32 + 1, q1);
        }
    }
}

// out[g,c] = gscr[g*32+c] / cnt_g + bf[c]; cnt via binary search on sorted batch
__global__ void finalize(const float* __restrict__ gscr, const int* __restrict__ batch,
                         const float* __restrict__ bf, float* __restrict__ out) {
    const int g = threadIdx.x;   // 128
    int lo = 0, hi = NN;
    while (lo < hi) { int m = (lo + hi) >> 1; if (batch[m] < g) lo = m + 1; else hi = m; }
    int lo2 = lo, hi2 = NN;
    while (lo2 < hi2) { int m = (lo2 + hi2) >> 1; if (batch[m] < g + 1) lo2 = m + 1; else hi2 = m; }
    const float inv = 1.f / fmaxf((float)(lo2 - lo), 1.f);
    out[g * 2]     = gscr[g * 32]     * inv + bf[0];
    out[g * 2 + 1] = gscr[g * 32 + 1] * inv + bf[1];
}

extern "C" void kernel_launch(void* const* d_in, const int* in_sizes, int n_in,
                              void* d_out, int out_size, void* d_ws, size_t ws_size,
                              hipStream_t stream) {
    const float* x       = (const float*)d_in[0];
    const float* W1      = (const float*)d_in[1];
    const float* att_src = (const float*)d_in[2];
    const float* att_dst = (const float*)d_in[3];
    const float* b1      = (const float*)d_in[4];
    const float* W2      = (const float*)d_in[5];
    const float* b2      = (const float*)d_in[6];
    const float* Wf      = (const float*)d_in[7];
    const float* bf      = (const float*)d_in[8];
    const int*   ei      = (const int*)d_in[9];
    const int*   batch   = (const int*)d_in[10];
    float* out = (float*)d_out;

    float* ws             = (float*)d_ws;
    float* hg             = ws;                                     // [NN*F] fp32 GAT out
    unsigned short* h1b   = (unsigned short*)(hg + (size_t)NN * F); // [NN*F] bf16 gemm1 out
    unsigned short* h2b   = h1b + (size_t)NN * F;                   // [NN*F] bf16 gemm2 out
    float* asrc      = (float*)(h2b + (size_t)NN * F);              // [NN]
    float* adst      = asrc + NN;                                   // [NN]
    float* dinv      = adst + NN;                                   // [NN]
    float* gscr      = dinv + NN;                                   // [NG*32]
    int*   row_start = (int*)(gscr + NG * 32);                      // [NN+1]
    unsigned short* csr16 = (unsigned short*)(row_start + NN + 1);  // [EP] (1.7MB, 4B-aligned)
    unsigned int*   ebuf  = (unsigned int*)(csr16 + EP);            // [EP]
    int*   cmat      = (int*)(ebuf + EP);                           // [CMAT]

    // CSR build: bucketed counting sort (no global atomics, dense writes)
    bin_count<<<NBE, 256, 0, stream>>>(ei, cmat);
    scan_all<<<1, 1024, 0, stream>>>(cmat);
    bin_scatter<<<NBE, 256, 0, stream>>>(ei, cmat, ebuf);
    bucket_sort<<<NBUCK, 256, 0, stream>>>(ebuf, cmat, row_start, csr16);
    hipMemsetAsync(gscr, 0, NG * 32 * sizeof(float), stream);

    gemm_tiled<<<(NN + 127) / 128, 512, 0, stream>>>(x, W1, h1b, NN,
                                                     att_src, att_dst, asrc, adst);
    gat_gather<<<(NN + 3) / 4, 256, 0, stream>>>(row_start, csr16, asrc, adst, h1b, b1, hg);
    gemm_tiled<<<(NN + 127) / 128, 512, 0, stream>>>(hg, W2, h2b, NN,
                                                     nullptr, nullptr, nullptr, nullptr);
    make_dinv<<<(NN + 255) / 256, 256, 0, stream>>>(row_start, dinv);
    gcn_gather_pool<<<(NN + 3) / 4, 256, 0, stream>>>(row_start, csr16, dinv, h2b, b2,
                                                      batch, Wf, gscr);
    finalize<<<1, NG, 0, stream>>>(gscr, batch, bf, out);
}

// Round 11
// 304.820 us; speedup vs baseline: 2.8208x; 1.0555x over previous
//
#include <hip/hip_runtime.h>

#define NN 50000
#define NE 800000
#define EP (NE + NN)      // edges + self loops = 850000
#define NG 128
#define F 128
#define NBE 208           // edge-pass blocks
#define EPB 4096          // edges per block (208*4096 >= EP)
#define NBUCK 196         // dst buckets of 256 nodes
#define CMAT (NBUCK * NBE)
#define BCAP 6144         // per-bucket edge cap (mean 4352)

typedef __attribute__((ext_vector_type(8))) short short8;
typedef __attribute__((ext_vector_type(4))) float float4v;
union U8 { uint4 u; short8 s; };

__device__ inline unsigned int bf16rn(float x) {   // RNE round to bf16 (low 16 bits)
    unsigned int u = __float_as_uint(x);
    u += 0x7fffu + ((u >> 16) & 1u);
    return u >> 16;
}
__device__ inline unsigned int pack2(float a, float b) {
    return bf16rn(a) | (bf16rn(b) << 16);
}
// 8 bf16 (uint4) -> 8 fma's into acc[0..7]
__device__ inline void bf8_fma(float* acc, float w, uint4 hv) {
    acc[0] = fmaf(w, __uint_as_float(hv.x << 16), acc[0]);
    acc[1] = fmaf(w, __uint_as_float(hv.x & 0xffff0000u), acc[1]);
    acc[2] = fmaf(w, __uint_as_float(hv.y << 16), acc[2]);
    acc[3] = fmaf(w, __uint_as_float(hv.y & 0xffff0000u), acc[3]);
    acc[4] = fmaf(w, __uint_as_float(hv.z << 16), acc[4]);
    acc[5] = fmaf(w, __uint_as_float(hv.z & 0xffff0000u), acc[5]);
    acc[6] = fmaf(w, __uint_as_float(hv.w << 16), acc[6]);
    acc[7] = fmaf(w, __uint_as_float(hv.w & 0xffff0000u), acc[7]);
}

// fp32 -> bf16 convert, 8 elements/thread
__global__ void cvt_bf16(const float* __restrict__ src, unsigned short* __restrict__ dst,
                         int n8) {
    const int i = blockIdx.x * blockDim.x + threadIdx.x;
    if (i >= n8) return;
    const float4 f0 = *(const float4*)(src + (size_t)i * 8);
    const float4 f1 = *(const float4*)(src + (size_t)i * 8 + 4);
    uint4 pk;
    pk.x = pack2(f0.x, f0.y); pk.y = pack2(f0.z, f0.w);
    pk.z = pack2(f1.x, f1.y); pk.w = pack2(f1.z, f1.w);
    *(uint4*)(dst + (size_t)i * 8) = pk;
}

// C[N,128] = A[N,128] @ W[128,128] via v_mfma_f32_16x16x32_bf16.
// A bf16 row-major (global), W fp32 (staged+repacked to B-fragments in LDS).
// 256 threads = 4 waves, 64 rows/block. C emitted bf16.
// Optional epilogue: asrc/adst = C @ att vectors, reduced from C-fragments.
// Layouts (verified m89/m91): A[m=l&15][k=(l>>4)*8+j]; B[k=(l>>4)*8+j][n=l&15];
// C/D: row=(l>>4)*4+r, col=l&15.
__global__ __launch_bounds__(256, 1) void mfma_gemm(
        const unsigned short* __restrict__ Ab, const float* __restrict__ W,
        unsigned short* __restrict__ Cb, int N,
        const float* __restrict__ att_src, const float* __restrict__ att_dst,
        float* __restrict__ asrc, float* __restrict__ adst) {
    __shared__ float wtmp[128 * 129];   // stride 129: frag-gather reads 2-way (free)
    __shared__ uint4 fragU[2048];       // 32 frags (kt 0..3, nt 0..7) x 64 lanes
    const int t = threadIdx.x;
    for (int i = t; i < 16384; i += 256)
        wtmp[(i >> 7) * 129 + (i & 127)] = W[i];
    __syncthreads();
    for (int p = t; p < 2048; p += 256) {   // consecutive lanes -> consecutive uint4
        const int f = p >> 6, l = p & 63;
        const int kt = f >> 3, nt = f & 7;
        const float* wp = wtmp + (kt * 32 + ((l >> 4) << 3)) * 129 + nt * 16 + (l & 15);
        uint4 pk;
        pk.x = pack2(wp[0],       wp[129]);
        pk.y = pack2(wp[2 * 129], wp[3 * 129]);
        pk.z = pack2(wp[4 * 129], wp[5 * 129]);
        pk.w = pack2(wp[6 * 129], wp[7 * 129]);
        fragU[p] = pk;
    }
    __syncthreads();
    const int wave = t >> 6, lane = t & 63;
    const int m0 = blockIdx.x * 64 + wave * 16;
    const int arow = m0 + (lane & 15);
    const int kq = (lane >> 4) << 3;
    U8 a[4];
#pragma unroll
    for (int kt = 0; kt < 4; ++kt) {
        if (arow < N) a[kt].u = *(const uint4*)(Ab + (size_t)arow * F + kt * 32 + kq);
        else          a[kt].u = make_uint4(0, 0, 0, 0);
    }
    const int ccol = lane & 15;
    const int crow0 = m0 + ((lane >> 4) << 2);
    float ps[4] = {}, pd[4] = {};
    for (int nt = 0; nt < 8; nt += 2) {
        float4v acc0 = {0.f, 0.f, 0.f, 0.f}, acc1 = {0.f, 0.f, 0.f, 0.f};
#pragma unroll
        for (int kt = 0; kt < 4; ++kt) {
            U8 b0, b1;
            b0.u = fragU[(kt * 8 + nt) * 64 + lane];
            b1.u = fragU[(kt * 8 + nt + 1) * 64 + lane];
            acc0 = __builtin_amdgcn_mfma_f32_16x16x32_bf16(a[kt].s, b0.s, acc0, 0, 0, 0);
            acc1 = __builtin_amdgcn_mfma_f32_16x16x32_bf16(a[kt].s, b1.s, acc1, 0, 0, 0);
        }
#pragma unroll
        for (int r = 0; r < 4; ++r) {
            const int row = crow0 + r;
            if (row < N) {
                Cb[(size_t)row * F + nt * 16 + ccol]       = (unsigned short)bf16rn(acc0[r]);
                Cb[(size_t)row * F + (nt + 1) * 16 + ccol] = (unsigned short)bf16rn(acc1[r]);
            }
        }
        if (asrc) {
            const float as0 = att_src[nt * 16 + ccol], as1 = att_src[(nt + 1) * 16 + ccol];
            const float ad0 = att_dst[nt * 16 + ccol], ad1 = att_dst[(nt + 1) * 16 + ccol];
#pragma unroll
            for (int r = 0; r < 4; ++r) {
                ps[r] += acc0[r] * as0 + acc1[r] * as1;
                pd[r] += acc0[r] * ad0 + acc1[r] * ad1;
            }
        }
    }
    if (asrc) {
#pragma unroll
        for (int r = 0; r < 4; ++r) {
            float s = ps[r], d = pd[r];
#pragma unroll
            for (int o = 8; o; o >>= 1) { s += __shfl_xor(s, o); d += __shfl_xor(d, o); }
            const int row = crow0 + r;
            if (ccol == 0 && row < N) { asrc[row] = s; adst[row] = d; }
        }
    }
}

// ---- CSR build via bucketed counting sort (bucket = dst>>8) ----
__global__ void bin_count(const int* __restrict__ ei, int* __restrict__ cmat) {
    __shared__ int lcnt[NBUCK];
    const int t = threadIdx.x, b = blockIdx.x;
    for (int i = t; i < NBUCK; i += 256) lcnt[i] = 0;
    __syncthreads();
    const int e0 = b * EPB;
#pragma unroll
    for (int i = 0; i < EPB / 256; ++i) {
        const int e = e0 + i * 256 + t;
        if (e < EP) {
            const int d = (e < NE) ? ei[NE + e] : e - NE;
            atomicAdd(&lcnt[d >> 8], 1);
        }
    }
    __syncthreads();
    for (int i = t; i < NBUCK; i += 256) cmat[i * NBE + b] = lcnt[i];
}

__global__ void scan_all(int* __restrict__ cmat) {
    __shared__ int part[1024];
    const int t = threadIdx.x;
    const int CH = (CMAT + 1023) / 1024;   // 40
    int loc[(CMAT + 1023) / 1024];
    const int lo = t * CH;
    int s = 0;
#pragma unroll
    for (int i = 0; i < CH; ++i) {
        const int j = lo + i;
        const int v = (j < CMAT) ? cmat[j] : 0;
        loc[i] = s; s += v;
    }
    part[t] = s;
    __syncthreads();
    for (int o = 1; o < 1024; o <<= 1) {
        const int u = (t >= o) ? part[t - o] : 0;
        __syncthreads();
        part[t] += u;
        __syncthreads();
    }
    const int base = part[t] - s;
#pragma unroll
    for (int i = 0; i < CH; ++i) {
        const int j = lo + i;
        if (j < CMAT) cmat[j] = base + loc[i];
    }
}

__global__ void bin_scatter(const int* __restrict__ ei, const int* __restrict__ cmat,
                            unsigned int* __restrict__ ebuf) {
    __shared__ int cur[NBUCK];
    const int t = threadIdx.x, b = blockIdx.x;
    for (int i = t; i < NBUCK; i += 256) cur[i] = cmat[i * NBE + b];
    __syncthreads();
    const int e0 = b * EPB;
#pragma unroll
    for (int i = 0; i < EPB / 256; ++i) {
        const int e = e0 + i * 256 + t;
        if (e < EP) {
            int s, d;
            if (e < NE) { s = ei[e]; d = ei[NE + e]; } else { s = d = e - NE; }
            const int p = atomicAdd(&cur[d >> 8], 1);
            ebuf[p] = (unsigned int)s | ((unsigned int)(d & 255) << 16);
        }
    }
}

__global__ void bucket_sort(const unsigned int* __restrict__ ebuf, const int* __restrict__ cmat,
                            int* __restrict__ row_start, unsigned short* __restrict__ csr16) {
    __shared__ unsigned int earr[BCAP];
    __shared__ unsigned short out16[BCAP];
    __shared__ int ecnt[256], epre[256];
    const int t = threadIdx.x, g = blockIdx.x;
    const int bstart = cmat[g * NBE];
    const int bend = (g == NBUCK - 1) ? EP : cmat[(g + 1) * NBE];
    const int m = bend - bstart;
    ecnt[t] = 0;
    __syncthreads();
    for (int i = t; i < m; i += 256) {
        const unsigned int v = ebuf[bstart + i];
        earr[i] = v;
        atomicAdd(&ecnt[v >> 16], 1);
    }
    __syncthreads();
    const int v0 = ecnt[t];
    epre[t] = v0;
    __syncthreads();
    for (int o = 1; o < 256; o <<= 1) {
        const int u = (t >= o) ? epre[t - o] : 0;
        __syncthreads();
        epre[t] += u;
        __syncthreads();
    }
    const int my_excl = epre[t] - v0;
    const int n = g * 256 + t;
    if (n <= NN) row_start[n] = bstart + my_excl;
    ecnt[t] = my_excl;
    __syncthreads();
    for (int i = t; i < m; i += 256) {
        const unsigned int v = earr[i];
        const int p = atomicAdd(&ecnt[v >> 16], 1);
        out16[p] = (unsigned short)(v & 0xffffu);
    }
    __syncthreads();
    for (int i = t; i < m; i += 256) csr16[bstart + i] = out16[i];
}

// ---- GAT gather: one wave per dst node over bf16 rows; emits bf16 rows.
__global__ void gat_gather(const int* __restrict__ row_start, const unsigned short* __restrict__ csr_src,
                           const float* __restrict__ asrc, const float* __restrict__ adst,
                           const unsigned short* __restrict__ hb, const float* __restrict__ bias,
                           unsigned short* __restrict__ out) {
    const int n = blockIdx.x * 4 + (threadIdx.x >> 6);
    const int lane = threadIdx.x & 63;
    if (n >= NN) return;
    const int quarter = lane >> 4;
    const int qo = (lane & 15) << 3;
    const int lo = row_start[n], hi = row_start[n + 1];
    const float adn = adst[n];
    float den = 0.f;
    float accA[8] = {}, accB[8] = {};
    for (int base = lo; base < hi; base += 64) {
        const int cnt = min(64, hi - base);
        const int sv = (lane < cnt) ? (int)csr_src[base + lane] : 0;
        float ev = 0.f;
        if (lane < cnt) {
            float sc = asrc[sv] + adn;
            sc = sc > 0.f ? sc : 0.2f * sc;
            ev = __expf(sc);
        }
        den += ev;
        int j = 0;
        for (; j + 16 <= cnt; j += 16) {
#pragma unroll
            for (int t = 0; t < 4; ++t) {
                const int jj = j + 4 * t + quarter;
                const int   s = __shfl(sv, jj);
                const float w = __shfl(ev, jj);
                const uint4 hv = *(const uint4*)(hb + (size_t)s * F + qo);
                bf8_fma((t & 1) ? accB : accA, w, hv);
            }
        }
        for (; j < cnt; j += 4) {
            const int jj = j + quarter;
            const int   s = __shfl(sv, jj);
            const float w = __shfl(ev, jj);
            const uint4 hv = *(const uint4*)(hb + (size_t)s * F + qo);
            bf8_fma(accA, w, hv);
        }
    }
    float acc[8];
#pragma unroll
    for (int i = 0; i < 8; ++i) {
        float v = accA[i] + accB[i];
        v += __shfl_xor(v, 16);
        v += __shfl_xor(v, 32);
        acc[i] = v;
    }
    for (int o = 32; o; o >>= 1) den += __shfl_xor(den, o);
    const float inv = 1.f / den;
    if (lane < 16) {
        float v[8];
#pragma unroll
        for (int i = 0; i < 8; ++i) {
            v[i] = fmaf(acc[i], inv, bias[qo + i]);
            v[i] = v[i] > 0.f ? v[i] : 0.f;
        }
        uint4 pk;
        pk.x = pack2(v[0], v[1]); pk.y = pack2(v[2], v[3]);
        pk.z = pack2(v[4], v[5]); pk.w = pack2(v[6], v[7]);
        *(uint4*)(out + (size_t)n * F + qo) = pk;
    }
}

__global__ void make_dinv(const int* __restrict__ row_start, float* __restrict__ dinv) {
    const int n = blockIdx.x * blockDim.x + threadIdx.x;
    if (n >= NN) return;
    dinv[n] = rsqrtf((float)(row_start[n + 1] - row_start[n]));
}

// ---- GCN gather over bf16 rows + fused mean-pool/head partials.
__global__ void gcn_gather_pool(const int* __restrict__ row_start, const unsigned short* __restrict__ csr_src,
                                const float* __restrict__ dinv, const unsigned short* __restrict__ hb,
                                const float* __restrict__ bias, const int* __restrict__ batch,
                                const float* __restrict__ Wf, float* __restrict__ gscr) {
    __shared__ int   sg[4];
    __shared__ float sp0[4], sp1[4];
    const int wave = threadIdx.x >> 6;
    const int n = blockIdx.x * 4 + wave;
    const int lane = threadIdx.x & 63;
    const int quarter = lane >> 4;
    const int qo = (lane & 15) << 3;
    if (threadIdx.x < 4) sg[threadIdx.x] = -1;
    float p0 = 0.f, p1 = 0.f;
    if (n < NN) {
        const int lo = row_start[n], hi = row_start[n + 1];
        const float dn = dinv[n];
        float accA[8] = {}, accB[8] = {};
        for (int base = lo; base < hi; base += 64) {
            const int cnt = min(64, hi - base);
            const int sv = (lane < cnt) ? (int)csr_src[base + lane] : 0;
            const float wv = (lane < cnt) ? dinv[sv] : 0.f;
            int j = 0;
            for (; j + 16 <= cnt; j += 16) {
#pragma unroll
                for (int t = 0; t < 4; ++t) {
                    const int jj = j + 4 * t + quarter;
                    const int   s = __shfl(sv, jj);
                    const float w = __shfl(wv, jj);
                    const uint4 hv = *(const uint4*)(hb + (size_t)s * F + qo);
                    bf8_fma((t & 1) ? accB : accA, w, hv);
                }
            }
            for (; j < cnt; j += 4) {
                const int jj = j + quarter;
                const int   s = __shfl(sv, jj);
                const float w = __shfl(wv, jj);
                const uint4 hv = *(const uint4*)(hb + (size_t)s * F + qo);
                bf8_fma(accA, w, hv);
            }
        }
        float v[8];
#pragma unroll
        for (int i = 0; i < 8; ++i) {
            float a = accA[i] + accB[i];
            a += __shfl_xor(a, 16);
            a += __shfl_xor(a, 32);
            v[i] = fmaf(a, dn, bias[qo + i]);
            v[i] = v[i] > 0.f ? v[i] : 0.f;
        }
        const float4 w0 = *(const float4*)(Wf + qo * 2);
        const float4 w1 = *(const float4*)(Wf + qo * 2 + 4);
        const float4 w2 = *(const float4*)(Wf + qo * 2 + 8);
        const float4 w3 = *(const float4*)(Wf + qo * 2 + 12);
        p0 = v[0]*w0.x + v[1]*w0.z + v[2]*w1.x + v[3]*w1.z +
             v[4]*w2.x + v[5]*w2.z + v[6]*w3.x + v[7]*w3.z;
        p1 = v[0]*w0.y + v[1]*w0.w + v[2]*w1.y + v[3]*w1.w +
             v[4]*w2.y + v[5]*w2.w + v[6]*w3.y + v[7]*w3.w;
        for (int o = 8; o; o >>= 1) { p0 += __shfl_xor(p0, o); p1 += __shfl_xor(p1, o); }
    }
    if (lane == 0 && n < NN) { sg[wave] = batch[n]; sp0[wave] = p0; sp1[wave] = p1; }
    __syncthreads();
    if (threadIdx.x == 0) {
#pragma unroll
        for (int w = 0; w < 4; ++w) {
            const int g = sg[w];
            if (g < 0) continue;
            float q0 = sp0[w], q1 = sp1[w];
            for (int u = w + 1; u < 4; ++u) {
                if (sg[u] == g) { q0 += sp0[u]; q1 += sp1[u]; sg[u] = -1; }
            }
            atomicAdd(gscr + g * 32,     q0);
            atomicAdd(gscr + g * 32 + 1, q1);
        }
    }
}

__global__ void finalize(const float* __restrict__ gscr, const int* __restrict__ batch,
                         const float* __restrict__ bf, float* __restrict__ out) {
    const int g = threadIdx.x;   // 128
    int lo = 0, hi = NN;
    while (lo < hi) { int m = (lo + hi) >> 1; if (batch[m] < g) lo = m + 1; else hi = m; }
    int lo2 = lo, hi2 = NN;
    while (lo2 < hi2) { int m = (lo2 + hi2) >> 1; if (batch[m] < g + 1) lo2 = m + 1; else hi2 = m; }
    const float inv = 1.f / fmaxf((float)(lo2 - lo), 1.f);
    out[g * 2]     = gscr[g * 32]     * inv + bf[0];
    out[g * 2 + 1] = gscr[g * 32 + 1] * inv + bf[1];
}

extern "C" void kernel_launch(void* const* d_in, const int* in_sizes, int n_in,
                              void* d_out, int out_size, void* d_ws, size_t ws_size,
                              hipStream_t stream) {
    const float* x       = (const float*)d_in[0];
    const float* W1      = (const float*)d_in[1];
    const float* att_src = (const float*)d_in[2];
    const float* att_dst = (const float*)d_in[3];
    const float* b1      = (const float*)d_in[4];
    const float* W2      = (const float*)d_in[5];
    const float* b2      = (const float*)d_in[6];
    const float* Wf      = (const float*)d_in[7];
    const float* bf      = (const float*)d_in[8];
    const int*   ei      = (const int*)d_in[9];
    const int*   batch   = (const int*)d_in[10];
    float* out = (float*)d_out;

    unsigned short* xb   = (unsigned short*)d_ws;                   // [NN*F] bf16 x
    unsigned short* h1b  = xb + (size_t)NN * F;                     // [NN*F] bf16 gemm1 out
    unsigned short* hgb  = h1b + (size_t)NN * F;                    // [NN*F] bf16 GAT out
    unsigned short* h2b  = hgb + (size_t)NN * F;                    // [NN*F] bf16 gemm2 out
    float* asrc      = (float*)(h2b + (size_t)NN * F);              // [NN]
    float* adst      = asrc + NN;                                   // [NN]
    float* dinv      = adst + NN;                                   // [NN]
    float* gscr      = dinv + NN;                                   // [NG*32]
    int*   row_start = (int*)(gscr + NG * 32);                      // [NN+1]
    unsigned short* csr16 = (unsigned short*)(row_start + NN + 1);  // [EP]
    unsigned int*   ebuf  = (unsigned int*)(csr16 + EP);            // [EP]
    int*   cmat      = (int*)(ebuf + EP);                           // [CMAT]

    // CSR build (bucketed counting sort) + input conversion
    bin_count<<<NBE, 256, 0, stream>>>(ei, cmat);
    cvt_bf16<<<(NN * F / 8 + 255) / 256, 256, 0, stream>>>(x, xb, NN * F / 8);
    scan_all<<<1, 1024, 0, stream>>>(cmat);
    bin_scatter<<<NBE, 256, 0, stream>>>(ei, cmat, ebuf);
    bucket_sort<<<NBUCK, 256, 0, stream>>>(ebuf, cmat, row_start, csr16);
    hipMemsetAsync(gscr, 0, NG * 32 * sizeof(float), stream);

    mfma_gemm<<<(NN + 63) / 64, 256, 0, stream>>>(xb, W1, h1b, NN,
                                                  att_src, att_dst, asrc, adst);
    gat_gather<<<(NN + 3) / 4, 256, 0, stream>>>(row_start, csr16, asrc, adst, h1b, b1, hgb);
    mfma_gemm<<<(NN + 63) / 64, 256, 0, stream>>>(hgb, W2, h2b, NN,
                                                  nullptr, nullptr, nullptr, nullptr);
    make_dinv<<<(NN + 255) / 256, 256, 0, stream>>>(row_start, dinv);
    gcn_gather_pool<<<(NN + 3) / 4, 256, 0, stream>>>(row_start, csr16, dinv, h2b, b2,
                                                      batch, Wf, gscr);
    finalize<<<1, NG, 0, stream>>>(gscr, batch, bf, out);
}